// Round 5
// baseline (806.841 us; speedup 1.0000x reference)
//
#include <hip/hip_runtime.h>

constexpr int N_NODES = 100000;
constexpr int N_EDGES = 1600000;
constexpr int D_IN   = 512;
constexpr int H_DIM  = 128;
constexpr int D_OUT  = 64;
constexpr float ALPHA = 0.1f;

constexpr int SCAN_TPB = 256;                 // threads per scan block
constexpr int SCAN_EPB = SCAN_TPB * 8;        // 2048 elems per block
constexpr int SCAN_NB  = (N_NODES + SCAN_EPB - 1) / SCAN_EPB;   // 49

typedef __attribute__((ext_vector_type(4))) float f32x4;
typedef __attribute__((ext_vector_type(8))) short bf16x8;

__device__ __forceinline__ unsigned short f2bf(float f) {
    unsigned int u = __float_as_uint(f);
    u += 0x7fff + ((u >> 16) & 1);          // RNE
    return (unsigned short)(u >> 16);
}
__device__ __forceinline__ float bf2f(unsigned short b) {
    return __uint_as_float(((unsigned int)b) << 16);
}

// ---------------- CSC build ----------------

__global__ void k_init(int* __restrict__ deg, int* __restrict__ cursor, int n) {
    int i = blockIdx.x * blockDim.x + threadIdx.x;
    if (i < n) { deg[i] = 0; cursor[i] = 0; }
}

__global__ void k_count(const int* __restrict__ col, int* __restrict__ deg, int e) {
    int i = blockIdx.x * blockDim.x + threadIdx.x;
    if (i < e) atomicAdd(&deg[col[i]], 1);
}

__global__ void k_dinv(const int* __restrict__ deg, float* __restrict__ dinv, int n) {
    int i = blockIdx.x * blockDim.x + threadIdx.x;
    if (i < n) dinv[i] = rsqrtf((float)(deg[i] + 1));   // +1 self loop
}

// ---- 3-phase hierarchical exclusive scan of deg -> offsets ----

__global__ __launch_bounds__(SCAN_TPB) void k_scan_part(const int* __restrict__ deg,
                                                        int* __restrict__ partials, int n) {
    __shared__ int red[SCAN_TPB];
    int t = threadIdx.x;
    int base = blockIdx.x * SCAN_EPB + t * 8;
    int s = 0;
    if (base + 8 <= n) {
        int4 a = *(const int4*)(deg + base);
        int4 b = *(const int4*)(deg + base + 4);
        s = a.x + a.y + a.z + a.w + b.x + b.y + b.z + b.w;
    } else {
        for (int j = 0; j < 8; ++j) if (base + j < n) s += deg[base + j];
    }
    red[t] = s;
    __syncthreads();
    for (int off = SCAN_TPB / 2; off > 0; off >>= 1) {
        if (t < off) red[t] += red[t + off];
        __syncthreads();
    }
    if (t == 0) partials[blockIdx.x] = red[0];
}

__global__ __launch_bounds__(64) void k_scan_mid(int* __restrict__ partials,
                                                 int* __restrict__ offsets) {
    __shared__ int buf[SCAN_NB];
    int t = threadIdx.x;
    if (t < SCAN_NB) buf[t] = partials[t];
    __syncthreads();
    if (t == 0) {
        int run = 0;
        for (int i = 0; i < SCAN_NB; ++i) { int v = buf[i]; buf[i] = run; run += v; }
        offsets[N_NODES] = run;    // == E
    }
    __syncthreads();
    if (t < SCAN_NB) partials[t] = buf[t];
}

__global__ __launch_bounds__(SCAN_TPB) void k_scan_write(const int* __restrict__ deg,
                                                         const int* __restrict__ partials,
                                                         int* __restrict__ offsets, int n) {
    __shared__ int sums[SCAN_TPB];
    int t = threadIdx.x;
    int base = blockIdx.x * SCAN_EPB + t * 8;
    int v[8];
    if (base + 8 <= n) {
        int4 a = *(const int4*)(deg + base);
        int4 b = *(const int4*)(deg + base + 4);
        v[0] = a.x; v[1] = a.y; v[2] = a.z; v[3] = a.w;
        v[4] = b.x; v[5] = b.y; v[6] = b.z; v[7] = b.w;
    } else {
        for (int j = 0; j < 8; ++j) v[j] = (base + j < n) ? deg[base + j] : 0;
    }
    int p[8], s = 0;
#pragma unroll
    for (int j = 0; j < 8; ++j) { p[j] = s; s += v[j]; }
    sums[t] = s;
    __syncthreads();
    // Hillis-Steele inclusive scan over thread sums
    for (int off = 1; off < SCAN_TPB; off <<= 1) {
        int add = (t >= off) ? sums[t - off] : 0;
        __syncthreads();
        sums[t] += add;
        __syncthreads();
    }
    int tbase = partials[blockIdx.x] + ((t == 0) ? 0 : sums[t - 1]);
#pragma unroll
    for (int j = 0; j < 8; ++j)
        if (base + j < n) offsets[base + j] = tbase + p[j];
}

__global__ void k_fill(const int* __restrict__ row, const int* __restrict__ col,
                       const int* __restrict__ offsets, int* __restrict__ cursor,
                       const float* __restrict__ dinv,
                       int* __restrict__ srcA, float* __restrict__ wgt, int e) {
    int i = blockIdx.x * blockDim.x + threadIdx.x;
    if (i >= e) return;
    int r = row[i], c = col[i];
    int p = offsets[c] + atomicAdd(&cursor[c], 1);
    srcA[p] = r;
    wgt[p]  = dinv[r] * dinv[c];
}

// ---------------- aggregation: one wave per node, bf16 gather, 4x unroll ----------------
// z = (1-a) * (dinv_i^2 * hb[i] + sum_in norm * hb[src]) + a * h0[i]

__global__ __launch_bounds__(256) void k_agg(
        const unsigned short* __restrict__ hb,   // bf16 rows [N][128] (current h)
        const float* __restrict__ h0,            // f32 residual
        const int* __restrict__ offsets, const int* __restrict__ srcA,
        const float* __restrict__ wgt, const float* __restrict__ dinv,
        float* __restrict__ z, int n) {
    int wid  = (int)((blockIdx.x * (unsigned)blockDim.x + threadIdx.x) >> 6);
    int lane = threadIdx.x & 63;
    if (wid >= n) return;
    float di = dinv[wid];
    const float oma = 1.0f - ALPHA;
    int o0 = offsets[wid], o1 = offsets[wid + 1];
    ushort2 hc = ((const ushort2*)(hb + (size_t)wid * H_DIM))[lane];
    float2 hz = ((const float2*)(h0 + (size_t)wid * H_DIM))[lane];
    float sw = oma * di * di;
    float accx = sw * bf2f(hc.x) + ALPHA * hz.x;
    float accy = sw * bf2f(hc.y) + ALPHA * hz.y;
    int p2 = o0;
    for (; p2 + 4 <= o1; p2 += 4) {
        int s0 = srcA[p2], s1 = srcA[p2 + 1], s2 = srcA[p2 + 2], s3 = srcA[p2 + 3];
        ushort2 g0 = ((const ushort2*)(hb + (size_t)s0 * H_DIM))[lane];
        ushort2 g1 = ((const ushort2*)(hb + (size_t)s1 * H_DIM))[lane];
        ushort2 g2 = ((const ushort2*)(hb + (size_t)s2 * H_DIM))[lane];
        ushort2 g3 = ((const ushort2*)(hb + (size_t)s3 * H_DIM))[lane];
        float w0 = oma * wgt[p2],     w1 = oma * wgt[p2 + 1];
        float w2 = oma * wgt[p2 + 2], w3 = oma * wgt[p2 + 3];
        accx += w0 * bf2f(g0.x); accy += w0 * bf2f(g0.y);
        accx += w1 * bf2f(g1.x); accy += w1 * bf2f(g1.y);
        accx += w2 * bf2f(g2.x); accy += w2 * bf2f(g2.y);
        accx += w3 * bf2f(g3.x); accy += w3 * bf2f(g3.y);
    }
    for (; p2 < o1; ++p2) {
        int s = srcA[p2];
        float wv = oma * wgt[p2];
        ushort2 g = ((const ushort2*)(hb + (size_t)s * H_DIM))[lane];
        accx += wv * bf2f(g.x); accy += wv * bf2f(g.y);
    }
    float2 o; o.x = accx; o.y = accy;
    ((float2*)(z + (size_t)wid * H_DIM))[lane] = o;
}

// ---------------- weight prep: f32 [K][N] -> bf16 hi/lo transposed [N][K] ----------------

__global__ void k_wprep(const float* __restrict__ w, unsigned short* __restrict__ hi,
                        unsigned short* __restrict__ lo, int K, int Nn) {
    int i = blockIdx.x * blockDim.x + threadIdx.x;
    if (i >= K * Nn) return;
    int n = i / K, k = i % K;
    float v = w[(size_t)k * Nn + n];
    unsigned short h = f2bf(v);
    hi[i] = h;
    lo[i] = f2bf(v - bf2f(h));
}

// ---------------- split-bf16 MFMA GEMM ----------------
// C = act(A @ B + bias); A f32 (converted in-kernel, LDS-staged, reg-prefetched),
// B pre-transposed bf16 hi/lo [BN][K] read DIRECTLY from global (L2-resident, no LDS).
// acc += Ah*Bh + Ah*Bl + Al*Bh (~f32 accuracy). Optional f32 and/or bf16 output.
// LDS = 32 KB -> 4 blocks/CU with VGPR<=128 (__launch_bounds__(256,4)).

template<int BN, bool RELU, bool BIAS, bool WF32, bool WB16>
__global__ __launch_bounds__(256, 4) void k_mfma_gemm(
        const float* __restrict__ A,
        const unsigned short* __restrict__ Bth,
        const unsigned short* __restrict__ Btl,
        const float* __restrict__ bias,
        float* __restrict__ C, unsigned short* __restrict__ Cb,
        int M, int K) {
    constexpr int BM = 128, BK = 64;
    constexpr int WN = BN / 2;       // per-wave cols (2x2 waves)
    constexpr int NF = WN / 16;      // 16x16 frags per wave in N
    __shared__ unsigned short Ah[BM * BK], Al[BM * BK];
    char* AhC = (char*)Ah; char* AlC = (char*)Al;
    const int tid = threadIdx.x;
    const int wave = tid >> 6, lane = tid & 63;
    const int wrow = wave >> 1, wcol = wave & 1;
    const int l15 = lane & 15, l4 = lane >> 4;
    const int bm = blockIdx.x * BM;

    // A staging coords: 4 chunks of 8 contiguous K-elems per thread
    int am[4], ak[4];
    bool aok[4];
#pragma unroll
    for (int c = 0; c < 4; ++c) {
        int ch = tid + c * 256;
        am[c] = ch >> 3; ak[c] = (ch & 7) * 8;
        aok[c] = (bm + am[c]) < M;
    }
    // per-lane B row base offset (elements): row = wcol*WN + nf*16 + l15
    const size_t bofs = (size_t)(wcol * WN + l15) * K + l4 * 8;

    f32x4 acc[4][NF];
#pragma unroll
    for (int mf = 0; mf < 4; ++mf)
#pragma unroll
        for (int nf = 0; nf < NF; ++nf) acc[mf][nf] = (f32x4){0.f, 0.f, 0.f, 0.f};

    // prologue: load A tile k0=0 into regs
    float va[4][8];
#pragma unroll
    for (int c = 0; c < 4; ++c) {
        if (aok[c]) {
            const float4* src = (const float4*)(A + (size_t)(bm + am[c]) * K + ak[c]);
            float4 a0 = src[0], a1 = src[1];
            va[c][0] = a0.x; va[c][1] = a0.y; va[c][2] = a0.z; va[c][3] = a0.w;
            va[c][4] = a1.x; va[c][5] = a1.y; va[c][6] = a1.z; va[c][7] = a1.w;
        } else {
#pragma unroll
            for (int j = 0; j < 8; ++j) va[c][j] = 0.f;
        }
    }

    for (int k0 = 0; k0 < K; k0 += BK) {
        // convert current A regs -> hi/lo, XOR-swizzled LDS write
#pragma unroll
        for (int c = 0; c < 4; ++c) {
            bf16x8 hv, lv;
#pragma unroll
            for (int j = 0; j < 8; ++j) {
                float v = va[c][j];
                unsigned short h = f2bf(v);
                hv[j] = (short)h;
                lv[j] = (short)f2bf(v - bf2f(h));
            }
            int byte = ((am[c] * BK + ak[c]) * 2) ^ ((am[c] & 7) << 4);
            *(bf16x8*)(AhC + byte) = hv;
            *(bf16x8*)(AlC + byte) = lv;
        }
        __syncthreads();
        // prefetch next A tile into regs (hides HBM latency under MFMA phase)
        if (k0 + BK < K) {
#pragma unroll
            for (int c = 0; c < 4; ++c) {
                if (aok[c]) {
                    const float4* src = (const float4*)(A + (size_t)(bm + am[c]) * K + (k0 + BK) + ak[c]);
                    float4 a0 = src[0], a1 = src[1];
                    va[c][0] = a0.x; va[c][1] = a0.y; va[c][2] = a0.z; va[c][3] = a0.w;
                    va[c][4] = a1.x; va[c][5] = a1.y; va[c][6] = a1.z; va[c][7] = a1.w;
                }
            }
        }
#pragma unroll
        for (int ks = 0; ks < 2; ++ks) {
            bf16x8 ah[4], al[4], bh[NF], bl[NF];
#pragma unroll
            for (int mf = 0; mf < 4; ++mf) {
                int row = wrow * 64 + mf * 16 + l15;
                int byte = ((row * BK + ks * 32 + l4 * 8) * 2) ^ ((row & 7) << 4);
                ah[mf] = *(const bf16x8*)(AhC + byte);
                al[mf] = *(const bf16x8*)(AlC + byte);
            }
#pragma unroll
            for (int nf = 0; nf < NF; ++nf) {
                size_t e = bofs + (size_t)nf * 16 * K + k0 + ks * 32;
                bh[nf] = *(const bf16x8*)(Bth + e);
                bl[nf] = *(const bf16x8*)(Btl + e);
            }
#pragma unroll
            for (int mf = 0; mf < 4; ++mf)
#pragma unroll
                for (int nf = 0; nf < NF; ++nf) {
                    acc[mf][nf] = __builtin_amdgcn_mfma_f32_16x16x32_bf16(ah[mf], bh[nf], acc[mf][nf], 0, 0, 0);
                    acc[mf][nf] = __builtin_amdgcn_mfma_f32_16x16x32_bf16(ah[mf], bl[nf], acc[mf][nf], 0, 0, 0);
                    acc[mf][nf] = __builtin_amdgcn_mfma_f32_16x16x32_bf16(al[mf], bh[nf], acc[mf][nf], 0, 0, 0);
                }
        }
        __syncthreads();
    }
    // epilogue: C/D layout col=lane&15, row=(lane>>4)*4+reg
#pragma unroll
    for (int mf = 0; mf < 4; ++mf) {
#pragma unroll
        for (int nf = 0; nf < NF; ++nf) {
            int col = wcol * WN + nf * 16 + l15;
            float bv = 0.f;
            if constexpr (BIAS) bv = bias[col];
#pragma unroll
            for (int r = 0; r < 4; ++r) {
                int grow = bm + wrow * 64 + mf * 16 + l4 * 4 + r;
                if (grow < M) {
                    float v = acc[mf][nf][r] + bv;
                    if constexpr (RELU) v = fmaxf(v, 0.f);
                    if constexpr (WF32) C[(size_t)grow * BN + col] = v;
                    if constexpr (WB16) Cb[(size_t)grow * BN + col] = f2bf(v);
                }
            }
        }
    }
}

// ---------------- launch ----------------

extern "C" void kernel_launch(void* const* d_in, const int* in_sizes, int n_in,
                              void* d_out, int out_size, void* d_ws, size_t ws_size,
                              hipStream_t stream) {
    const float* x  = (const float*)d_in[0];
    const int*   ei = (const int*)d_in[1];
    const float* w1 = (const float*)d_in[2];
    const float* b1 = (const float*)d_in[3];
    const float* cw = (const float*)d_in[4];
    const float* w2 = (const float*)d_in[5];
    const float* b2 = (const float*)d_in[6];
    float* out = (float*)d_out;
    const int* rowp = ei;            // source nodes
    const int* colp = ei + N_EDGES;  // target nodes

    char* p = (char*)d_ws;
    auto alloc = [&](size_t bytes) -> void* {
        void* r = (void*)p;
        p += ((bytes + 255) / 256) * 256;
        return r;
    };
    int*   deg     = (int*)  alloc((size_t)N_NODES * 4);
    int*   cursor  = (int*)  alloc((size_t)N_NODES * 4);
    int*   offsets = (int*)  alloc((size_t)(N_NODES + 1) * 4);
    int*   partials= (int*)  alloc((size_t)SCAN_NB * 4);
    int*   srcA    = (int*)  alloc((size_t)N_EDGES * 4);
    float* wgt     = (float*)alloc((size_t)N_EDGES * 4);
    float* dinv    = (float*)alloc((size_t)N_NODES * 4);
    float* h0      = (float*)alloc((size_t)N_NODES * H_DIM * 4);
    float* z       = (float*)alloc((size_t)N_NODES * H_DIM * 4);
    unsigned short* h0b = (unsigned short*)alloc((size_t)N_NODES * H_DIM * 2);
    unsigned short* h1b = (unsigned short*)alloc((size_t)N_NODES * H_DIM * 2);
    unsigned short* w1th = (unsigned short*)alloc((size_t)H_DIM * D_IN * 2);
    unsigned short* w1tl = (unsigned short*)alloc((size_t)H_DIM * D_IN * 2);
    unsigned short* cwth = (unsigned short*)alloc((size_t)2 * H_DIM * H_DIM * 2);
    unsigned short* cwtl = (unsigned short*)alloc((size_t)2 * H_DIM * H_DIM * 2);
    unsigned short* w2th = (unsigned short*)alloc((size_t)D_OUT * H_DIM * 2);
    unsigned short* w2tl = (unsigned short*)alloc((size_t)D_OUT * H_DIM * 2);

    float* h2     = out;                              // output 0: h [N,128]
    float* logits = out + (size_t)N_NODES * H_DIM;    // output 1: [N,64]

    // CSC build
    hipLaunchKernelGGL(k_init,  dim3((N_NODES + 255) / 256), dim3(256), 0, stream, deg, cursor, N_NODES);
    hipLaunchKernelGGL(k_count, dim3((N_EDGES + 255) / 256), dim3(256), 0, stream, colp, deg, N_EDGES);
    hipLaunchKernelGGL(k_dinv,  dim3((N_NODES + 255) / 256), dim3(256), 0, stream, deg, dinv, N_NODES);
    hipLaunchKernelGGL(k_scan_part,  dim3(SCAN_NB), dim3(SCAN_TPB), 0, stream, deg, partials, N_NODES);
    hipLaunchKernelGGL(k_scan_mid,   dim3(1), dim3(64), 0, stream, partials, offsets);
    hipLaunchKernelGGL(k_scan_write, dim3(SCAN_NB), dim3(SCAN_TPB), 0, stream, deg, partials, offsets, N_NODES);
    hipLaunchKernelGGL(k_fill,  dim3((N_EDGES + 255) / 256), dim3(256), 0, stream,
                       rowp, colp, offsets, cursor, dinv, srcA, wgt, N_EDGES);

    // weight prep (tiny)
    hipLaunchKernelGGL(k_wprep, dim3((D_IN * H_DIM + 255) / 256), dim3(256), 0, stream,
                       w1, w1th, w1tl, D_IN, H_DIM);
    hipLaunchKernelGGL(k_wprep, dim3((H_DIM * H_DIM + 255) / 256), dim3(256), 0, stream,
                       cw, cwth, cwtl, H_DIM, H_DIM);
    hipLaunchKernelGGL(k_wprep, dim3((H_DIM * H_DIM + 255) / 256), dim3(256), 0, stream,
                       cw + H_DIM * H_DIM, cwth + H_DIM * H_DIM, cwtl + H_DIM * H_DIM, H_DIM, H_DIM);
    hipLaunchKernelGGL(k_wprep, dim3((H_DIM * D_OUT + 255) / 256), dim3(256), 0, stream,
                       w2, w2th, w2tl, H_DIM, D_OUT);

    int gemmGrid = (N_NODES + 127) / 128;
    // h0 = relu(x @ w1 + b1): f32 + bf16 copies
    hipLaunchKernelGGL((k_mfma_gemm<128, true, true, true, true>), dim3(gemmGrid), dim3(256), 0, stream,
                       x, w1th, w1tl, b1, h0, h0b, N_NODES, D_IN);

    int aggGrid = (int)(((size_t)N_NODES * 64 + 255) / 256);
    // layer 0
    hipLaunchKernelGGL(k_agg, dim3(aggGrid), dim3(256), 0, stream,
                       h0b, h0, offsets, srcA, wgt, dinv, z, N_NODES);
    hipLaunchKernelGGL((k_mfma_gemm<128, false, false, false, true>), dim3(gemmGrid), dim3(256), 0, stream,
                       z, cwth, cwtl, (const float*)nullptr, (float*)nullptr, h1b, N_NODES, H_DIM);
    // layer 1
    hipLaunchKernelGGL(k_agg, dim3(aggGrid), dim3(256), 0, stream,
                       h1b, h0, offsets, srcA, wgt, dinv, z, N_NODES);
    hipLaunchKernelGGL((k_mfma_gemm<128, false, false, true, false>), dim3(gemmGrid), dim3(256), 0, stream,
                       z, cwth + H_DIM * H_DIM, cwtl + H_DIM * H_DIM, (const float*)nullptr, h2,
                       (unsigned short*)nullptr, N_NODES, H_DIM);
    // logits = h2 @ w2 + b2
    hipLaunchKernelGGL((k_mfma_gemm<64, false, true, true, false>), dim3(gemmGrid), dim3(256), 0, stream,
                       h2, w2th, w2tl, b2, logits, (unsigned short*)nullptr, N_NODES, H_DIM);
}

// Round 6
// 604.147 us; speedup vs baseline: 1.3355x; 1.3355x over previous
//
#include <hip/hip_runtime.h>

constexpr int N_NODES = 100000;
constexpr int N_EDGES = 1600000;
constexpr int D_IN   = 512;
constexpr int H_DIM  = 128;
constexpr int D_OUT  = 64;
constexpr float ALPHA = 0.1f;

constexpr int SCAN_TPB = 256;                 // threads per scan block
constexpr int SCAN_EPB = SCAN_TPB * 8;        // 2048 elems per block
constexpr int SCAN_NB  = (N_NODES + SCAN_EPB - 1) / SCAN_EPB;   // 49

typedef __attribute__((ext_vector_type(4))) float f32x4;
typedef __attribute__((ext_vector_type(8))) short bf16x8;

__device__ __forceinline__ unsigned short f2bf(float f) {
    unsigned int u = __float_as_uint(f);
    u += 0x7fff + ((u >> 16) & 1);          // RNE
    return (unsigned short)(u >> 16);
}
__device__ __forceinline__ float bf2f(unsigned short b) {
    return __uint_as_float(((unsigned int)b) << 16);
}

// ---------------- CSC build ----------------

__global__ void k_init(int* __restrict__ deg, int* __restrict__ cursor, int n) {
    int i = blockIdx.x * blockDim.x + threadIdx.x;
    if (i < n) { deg[i] = 0; cursor[i] = 0; }
}

__global__ void k_count(const int* __restrict__ col, int* __restrict__ deg, int e) {
    int i = blockIdx.x * blockDim.x + threadIdx.x;
    if (i < e) atomicAdd(&deg[col[i]], 1);
}

__global__ void k_dinv(const int* __restrict__ deg, float* __restrict__ dinv, int n) {
    int i = blockIdx.x * blockDim.x + threadIdx.x;
    if (i < n) dinv[i] = rsqrtf((float)(deg[i] + 1));   // +1 self loop
}

// ---- 3-phase hierarchical exclusive scan of deg -> offsets ----

__global__ __launch_bounds__(SCAN_TPB) void k_scan_part(const int* __restrict__ deg,
                                                        int* __restrict__ partials, int n) {
    __shared__ int red[SCAN_TPB];
    int t = threadIdx.x;
    int base = blockIdx.x * SCAN_EPB + t * 8;
    int s = 0;
    if (base + 8 <= n) {
        int4 a = *(const int4*)(deg + base);
        int4 b = *(const int4*)(deg + base + 4);
        s = a.x + a.y + a.z + a.w + b.x + b.y + b.z + b.w;
    } else {
        for (int j = 0; j < 8; ++j) if (base + j < n) s += deg[base + j];
    }
    red[t] = s;
    __syncthreads();
    for (int off = SCAN_TPB / 2; off > 0; off >>= 1) {
        if (t < off) red[t] += red[t + off];
        __syncthreads();
    }
    if (t == 0) partials[blockIdx.x] = red[0];
}

__global__ __launch_bounds__(64) void k_scan_mid(int* __restrict__ partials,
                                                 int* __restrict__ offsets) {
    __shared__ int buf[SCAN_NB];
    int t = threadIdx.x;
    if (t < SCAN_NB) buf[t] = partials[t];
    __syncthreads();
    if (t == 0) {
        int run = 0;
        for (int i = 0; i < SCAN_NB; ++i) { int v = buf[i]; buf[i] = run; run += v; }
        offsets[N_NODES] = run;    // == E
    }
    __syncthreads();
    if (t < SCAN_NB) partials[t] = buf[t];
}

__global__ __launch_bounds__(SCAN_TPB) void k_scan_write(const int* __restrict__ deg,
                                                         const int* __restrict__ partials,
                                                         int* __restrict__ offsets, int n) {
    __shared__ int sums[SCAN_TPB];
    int t = threadIdx.x;
    int base = blockIdx.x * SCAN_EPB + t * 8;
    int v[8];
    if (base + 8 <= n) {
        int4 a = *(const int4*)(deg + base);
        int4 b = *(const int4*)(deg + base + 4);
        v[0] = a.x; v[1] = a.y; v[2] = a.z; v[3] = a.w;
        v[4] = b.x; v[5] = b.y; v[6] = b.z; v[7] = b.w;
    } else {
        for (int j = 0; j < 8; ++j) v[j] = (base + j < n) ? deg[base + j] : 0;
    }
    int p[8], s = 0;
#pragma unroll
    for (int j = 0; j < 8; ++j) { p[j] = s; s += v[j]; }
    sums[t] = s;
    __syncthreads();
    // Hillis-Steele inclusive scan over thread sums
    for (int off = 1; off < SCAN_TPB; off <<= 1) {
        int add = (t >= off) ? sums[t - off] : 0;
        __syncthreads();
        sums[t] += add;
        __syncthreads();
    }
    int tbase = partials[blockIdx.x] + ((t == 0) ? 0 : sums[t - 1]);
#pragma unroll
    for (int j = 0; j < 8; ++j)
        if (base + j < n) offsets[base + j] = tbase + p[j];
}

__global__ void k_fill(const int* __restrict__ row, const int* __restrict__ col,
                       const int* __restrict__ offsets, int* __restrict__ cursor,
                       const float* __restrict__ dinv,
                       int* __restrict__ srcA, float* __restrict__ wgt, int e) {
    int i = blockIdx.x * blockDim.x + threadIdx.x;
    if (i >= e) return;
    int r = row[i], c = col[i];
    int p = offsets[c] + atomicAdd(&cursor[c], 1);
    srcA[p] = r;
    wgt[p]  = dinv[r] * dinv[c];
}

// ---------------- aggregation: one wave per node, bf16 gather, 4x unroll ----------------
// z = (1-a) * (dinv_i^2 * hb[i] + sum_in norm * hb[src]) + a * h0[i]

__global__ __launch_bounds__(256) void k_agg(
        const unsigned short* __restrict__ hb,   // bf16 rows [N][128] (current h)
        const float* __restrict__ h0,            // f32 residual
        const int* __restrict__ offsets, const int* __restrict__ srcA,
        const float* __restrict__ wgt, const float* __restrict__ dinv,
        float* __restrict__ z, int n) {
    int wid  = (int)((blockIdx.x * (unsigned)blockDim.x + threadIdx.x) >> 6);
    int lane = threadIdx.x & 63;
    if (wid >= n) return;
    float di = dinv[wid];
    const float oma = 1.0f - ALPHA;
    int o0 = offsets[wid], o1 = offsets[wid + 1];
    ushort2 hc = ((const ushort2*)(hb + (size_t)wid * H_DIM))[lane];
    float2 hz = ((const float2*)(h0 + (size_t)wid * H_DIM))[lane];
    float sw = oma * di * di;
    float accx = sw * bf2f(hc.x) + ALPHA * hz.x;
    float accy = sw * bf2f(hc.y) + ALPHA * hz.y;
    int p2 = o0;
    for (; p2 + 4 <= o1; p2 += 4) {
        int s0 = srcA[p2], s1 = srcA[p2 + 1], s2 = srcA[p2 + 2], s3 = srcA[p2 + 3];
        ushort2 g0 = ((const ushort2*)(hb + (size_t)s0 * H_DIM))[lane];
        ushort2 g1 = ((const ushort2*)(hb + (size_t)s1 * H_DIM))[lane];
        ushort2 g2 = ((const ushort2*)(hb + (size_t)s2 * H_DIM))[lane];
        ushort2 g3 = ((const ushort2*)(hb + (size_t)s3 * H_DIM))[lane];
        float w0 = oma * wgt[p2],     w1 = oma * wgt[p2 + 1];
        float w2 = oma * wgt[p2 + 2], w3 = oma * wgt[p2 + 3];
        accx += w0 * bf2f(g0.x); accy += w0 * bf2f(g0.y);
        accx += w1 * bf2f(g1.x); accy += w1 * bf2f(g1.y);
        accx += w2 * bf2f(g2.x); accy += w2 * bf2f(g2.y);
        accx += w3 * bf2f(g3.x); accy += w3 * bf2f(g3.y);
    }
    for (; p2 < o1; ++p2) {
        int s = srcA[p2];
        float wv = oma * wgt[p2];
        ushort2 g = ((const ushort2*)(hb + (size_t)s * H_DIM))[lane];
        accx += wv * bf2f(g.x); accy += wv * bf2f(g.y);
    }
    float2 o; o.x = accx; o.y = accy;
    ((float2*)(z + (size_t)wid * H_DIM))[lane] = o;
}

// ---------------- weight prep: f32 [K][N] -> bf16 hi/lo transposed [N][K] ----------------

__global__ void k_wprep(const float* __restrict__ w, unsigned short* __restrict__ hi,
                        unsigned short* __restrict__ lo, int K, int Nn) {
    int i = blockIdx.x * blockDim.x + threadIdx.x;
    if (i >= K * Nn) return;
    int n = i / K, k = i % K;
    float v = w[(size_t)k * Nn + n];
    unsigned short h = f2bf(v);
    hi[i] = h;
    lo[i] = f2bf(v - bf2f(h));
}

// ---------------- split-bf16 MFMA GEMM ----------------
// C = act(A @ B + bias); A f32 converted to hi/lo bf16 during LDS staging,
// B pre-transposed bf16 hi/lo [BN][K] read DIRECTLY from global (L2-resident, no LDS).
// acc += Ah*Bh + Ah*Bl + Al*Bh (~f32 accuracy). Optional f32 and/or bf16 output.
// LDS = 32 KB; __launch_bounds__(256,3) -> VGPR cap ~168 (no spill, ~150 needed),
// 3 blocks/CU. (256,4) spilled: VGPR forced to 64, 840 MB scratch traffic, 2.5x slower.

template<int BN, bool RELU, bool BIAS, bool WF32, bool WB16>
__global__ __launch_bounds__(256, 3) void k_mfma_gemm(
        const float* __restrict__ A,
        const unsigned short* __restrict__ Bth,
        const unsigned short* __restrict__ Btl,
        const float* __restrict__ bias,
        float* __restrict__ C, unsigned short* __restrict__ Cb,
        int M, int K) {
    constexpr int BM = 128, BK = 64;
    constexpr int WN = BN / 2;       // per-wave cols (2x2 waves)
    constexpr int NF = WN / 16;      // 16x16 frags per wave in N
    __shared__ unsigned short Ah[BM * BK], Al[BM * BK];
    char* AhC = (char*)Ah; char* AlC = (char*)Al;
    const int tid = threadIdx.x;
    const int wave = tid >> 6, lane = tid & 63;
    const int wrow = wave >> 1, wcol = wave & 1;
    const int l15 = lane & 15, l4 = lane >> 4;
    const int bm = blockIdx.x * BM;

    // per-lane B row base offset (elements): row = wcol*WN + l15 (+nf*16)
    const size_t bofs = (size_t)(wcol * WN + l15) * K + l4 * 8;

    f32x4 acc[4][NF];
#pragma unroll
    for (int mf = 0; mf < 4; ++mf)
#pragma unroll
        for (int nf = 0; nf < NF; ++nf) acc[mf][nf] = (f32x4){0.f, 0.f, 0.f, 0.f};

    for (int k0 = 0; k0 < K; k0 += BK) {
        // stage A: f32 -> hi/lo bf16, XOR-swizzled LDS
#pragma unroll
        for (int c = 0; c < 4; ++c) {
            int ch = tid + c * 256;          // chunk = 8 elems along K
            int m = ch >> 3, kc = (ch & 7) * 8;
            int gr = bm + m;
            float v[8];
            if (gr < M) {
                const float4* src = (const float4*)(A + (size_t)gr * K + k0 + kc);
                float4 a0 = src[0], a1 = src[1];
                v[0] = a0.x; v[1] = a0.y; v[2] = a0.z; v[3] = a0.w;
                v[4] = a1.x; v[5] = a1.y; v[6] = a1.z; v[7] = a1.w;
            } else {
#pragma unroll
                for (int j = 0; j < 8; ++j) v[j] = 0.f;
            }
            bf16x8 hv, lv;
#pragma unroll
            for (int j = 0; j < 8; ++j) {
                unsigned short h = f2bf(v[j]);
                hv[j] = (short)h;
                lv[j] = (short)f2bf(v[j] - bf2f(h));
            }
            int byte = ((m * BK + kc) * 2) ^ ((m & 7) << 4);
            *(bf16x8*)(AhC + byte) = hv;
            *(bf16x8*)(AlC + byte) = lv;
        }
        __syncthreads();
#pragma unroll
        for (int ks = 0; ks < 2; ++ks) {
            bf16x8 ah[4], al[4], bh[NF], bl[NF];
#pragma unroll
            for (int mf = 0; mf < 4; ++mf) {
                int row = wrow * 64 + mf * 16 + l15;
                int byte = ((row * BK + ks * 32 + l4 * 8) * 2) ^ ((row & 7) << 4);
                ah[mf] = *(const bf16x8*)(AhC + byte);
                al[mf] = *(const bf16x8*)(AlC + byte);
            }
#pragma unroll
            for (int nf = 0; nf < NF; ++nf) {
                size_t e = bofs + (size_t)nf * 16 * K + k0 + ks * 32;
                bh[nf] = *(const bf16x8*)(Bth + e);
                bl[nf] = *(const bf16x8*)(Btl + e);
            }
#pragma unroll
            for (int mf = 0; mf < 4; ++mf)
#pragma unroll
                for (int nf = 0; nf < NF; ++nf) {
                    acc[mf][nf] = __builtin_amdgcn_mfma_f32_16x16x32_bf16(ah[mf], bh[nf], acc[mf][nf], 0, 0, 0);
                    acc[mf][nf] = __builtin_amdgcn_mfma_f32_16x16x32_bf16(ah[mf], bl[nf], acc[mf][nf], 0, 0, 0);
                    acc[mf][nf] = __builtin_amdgcn_mfma_f32_16x16x32_bf16(al[mf], bh[nf], acc[mf][nf], 0, 0, 0);
                }
        }
        __syncthreads();
    }
    // epilogue: C/D layout col=lane&15, row=(lane>>4)*4+reg
#pragma unroll
    for (int mf = 0; mf < 4; ++mf) {
#pragma unroll
        for (int nf = 0; nf < NF; ++nf) {
            int col = wcol * WN + nf * 16 + l15;
            float bv = 0.f;
            if constexpr (BIAS) bv = bias[col];
#pragma unroll
            for (int r = 0; r < 4; ++r) {
                int grow = bm + wrow * 64 + mf * 16 + l4 * 4 + r;
                if (grow < M) {
                    float v = acc[mf][nf][r] + bv;
                    if constexpr (RELU) v = fmaxf(v, 0.f);
                    if constexpr (WF32) C[(size_t)grow * BN + col] = v;
                    if constexpr (WB16) Cb[(size_t)grow * BN + col] = f2bf(v);
                }
            }
        }
    }
}

// ---------------- launch ----------------

extern "C" void kernel_launch(void* const* d_in, const int* in_sizes, int n_in,
                              void* d_out, int out_size, void* d_ws, size_t ws_size,
                              hipStream_t stream) {
    const float* x  = (const float*)d_in[0];
    const int*   ei = (const int*)d_in[1];
    const float* w1 = (const float*)d_in[2];
    const float* b1 = (const float*)d_in[3];
    const float* cw = (const float*)d_in[4];
    const float* w2 = (const float*)d_in[5];
    const float* b2 = (const float*)d_in[6];
    float* out = (float*)d_out;
    const int* rowp = ei;            // source nodes
    const int* colp = ei + N_EDGES;  // target nodes

    char* p = (char*)d_ws;
    auto alloc = [&](size_t bytes) -> void* {
        void* r = (void*)p;
        p += ((bytes + 255) / 256) * 256;
        return r;
    };
    int*   deg     = (int*)  alloc((size_t)N_NODES * 4);
    int*   cursor  = (int*)  alloc((size_t)N_NODES * 4);
    int*   offsets = (int*)  alloc((size_t)(N_NODES + 1) * 4);
    int*   partials= (int*)  alloc((size_t)SCAN_NB * 4);
    int*   srcA    = (int*)  alloc((size_t)N_EDGES * 4);
    float* wgt     = (float*)alloc((size_t)N_EDGES * 4);
    float* dinv    = (float*)alloc((size_t)N_NODES * 4);
    float* h0      = (float*)alloc((size_t)N_NODES * H_DIM * 4);
    float* z       = (float*)alloc((size_t)N_NODES * H_DIM * 4);
    unsigned short* h0b = (unsigned short*)alloc((size_t)N_NODES * H_DIM * 2);
    unsigned short* h1b = (unsigned short*)alloc((size_t)N_NODES * H_DIM * 2);
    unsigned short* w1th = (unsigned short*)alloc((size_t)H_DIM * D_IN * 2);
    unsigned short* w1tl = (unsigned short*)alloc((size_t)H_DIM * D_IN * 2);
    unsigned short* cwth = (unsigned short*)alloc((size_t)2 * H_DIM * H_DIM * 2);
    unsigned short* cwtl = (unsigned short*)alloc((size_t)2 * H_DIM * H_DIM * 2);
    unsigned short* w2th = (unsigned short*)alloc((size_t)D_OUT * H_DIM * 2);
    unsigned short* w2tl = (unsigned short*)alloc((size_t)D_OUT * H_DIM * 2);

    float* h2     = out;                              // output 0: h [N,128]
    float* logits = out + (size_t)N_NODES * H_DIM;    // output 1: [N,64]

    // CSC build
    hipLaunchKernelGGL(k_init,  dim3((N_NODES + 255) / 256), dim3(256), 0, stream, deg, cursor, N_NODES);
    hipLaunchKernelGGL(k_count, dim3((N_EDGES + 255) / 256), dim3(256), 0, stream, colp, deg, N_EDGES);
    hipLaunchKernelGGL(k_dinv,  dim3((N_NODES + 255) / 256), dim3(256), 0, stream, deg, dinv, N_NODES);
    hipLaunchKernelGGL(k_scan_part,  dim3(SCAN_NB), dim3(SCAN_TPB), 0, stream, deg, partials, N_NODES);
    hipLaunchKernelGGL(k_scan_mid,   dim3(1), dim3(64), 0, stream, partials, offsets);
    hipLaunchKernelGGL(k_scan_write, dim3(SCAN_NB), dim3(SCAN_TPB), 0, stream, deg, partials, offsets, N_NODES);
    hipLaunchKernelGGL(k_fill,  dim3((N_EDGES + 255) / 256), dim3(256), 0, stream,
                       rowp, colp, offsets, cursor, dinv, srcA, wgt, N_EDGES);

    // weight prep (tiny)
    hipLaunchKernelGGL(k_wprep, dim3((D_IN * H_DIM + 255) / 256), dim3(256), 0, stream,
                       w1, w1th, w1tl, D_IN, H_DIM);
    hipLaunchKernelGGL(k_wprep, dim3((H_DIM * H_DIM + 255) / 256), dim3(256), 0, stream,
                       cw, cwth, cwtl, H_DIM, H_DIM);
    hipLaunchKernelGGL(k_wprep, dim3((H_DIM * H_DIM + 255) / 256), dim3(256), 0, stream,
                       cw + H_DIM * H_DIM, cwth + H_DIM * H_DIM, cwtl + H_DIM * H_DIM, H_DIM, H_DIM);
    hipLaunchKernelGGL(k_wprep, dim3((H_DIM * D_OUT + 255) / 256), dim3(256), 0, stream,
                       w2, w2th, w2tl, H_DIM, D_OUT);

    int gemmGrid = (N_NODES + 127) / 128;
    // h0 = relu(x @ w1 + b1): f32 + bf16 copies
    hipLaunchKernelGGL((k_mfma_gemm<128, true, true, true, true>), dim3(gemmGrid), dim3(256), 0, stream,
                       x, w1th, w1tl, b1, h0, h0b, N_NODES, D_IN);

    int aggGrid = (int)(((size_t)N_NODES * 64 + 255) / 256);
    // layer 0
    hipLaunchKernelGGL(k_agg, dim3(aggGrid), dim3(256), 0, stream,
                       h0b, h0, offsets, srcA, wgt, dinv, z, N_NODES);
    hipLaunchKernelGGL((k_mfma_gemm<128, false, false, false, true>), dim3(gemmGrid), dim3(256), 0, stream,
                       z, cwth, cwtl, (const float*)nullptr, (float*)nullptr, h1b, N_NODES, H_DIM);
    // layer 1
    hipLaunchKernelGGL(k_agg, dim3(aggGrid), dim3(256), 0, stream,
                       h1b, h0, offsets, srcA, wgt, dinv, z, N_NODES);
    hipLaunchKernelGGL((k_mfma_gemm<128, false, false, true, false>), dim3(gemmGrid), dim3(256), 0, stream,
                       z, cwth + H_DIM * H_DIM, cwtl + H_DIM * H_DIM, (const float*)nullptr, h2,
                       (unsigned short*)nullptr, N_NODES, H_DIM);
    // logits = h2 @ w2 + b2
    hipLaunchKernelGGL((k_mfma_gemm<64, false, true, true, false>), dim3(gemmGrid), dim3(256), 0, stream,
                       h2, w2th, w2tl, b2, logits, (unsigned short*)nullptr, N_NODES, H_DIM);
}

// Round 7
// 502.612 us; speedup vs baseline: 1.6053x; 1.2020x over previous
//
#include <hip/hip_runtime.h>

constexpr int N_NODES = 100000;
constexpr int N_EDGES = 1600000;
constexpr int D_IN   = 512;
constexpr int H_DIM  = 128;
constexpr int D_OUT  = 64;
constexpr float ALPHA = 0.1f;

constexpr int SCAN_TPB = 256;                 // threads per scan block
constexpr int SCAN_EPB = SCAN_TPB * 8;        // 2048 elems per block
constexpr int SCAN_NB  = (N_NODES + SCAN_EPB - 1) / SCAN_EPB;   // 49

typedef __attribute__((ext_vector_type(4))) float f32x4;
typedef __attribute__((ext_vector_type(8))) short bf16x8;

__device__ __forceinline__ unsigned short f2bf(float f) {
    unsigned int u = __float_as_uint(f);
    u += 0x7fff + ((u >> 16) & 1);          // RNE
    return (unsigned short)(u >> 16);
}
__device__ __forceinline__ float bf2f(unsigned short b) {
    return __uint_as_float(((unsigned int)b) << 16);
}

// ---------------- CSC build ----------------

__global__ void k_init(int* __restrict__ deg, int* __restrict__ cursor, int n) {
    int i = blockIdx.x * blockDim.x + threadIdx.x;
    if (i < n) { deg[i] = 0; cursor[i] = 0; }
}

__global__ void k_count(const int* __restrict__ col, int* __restrict__ deg, int e) {
    int i = blockIdx.x * blockDim.x + threadIdx.x;
    if (i < e) atomicAdd(&deg[col[i]], 1);
}

__global__ void k_dinv(const int* __restrict__ deg, float* __restrict__ dinv, int n) {
    int i = blockIdx.x * blockDim.x + threadIdx.x;
    if (i < n) dinv[i] = rsqrtf((float)(deg[i] + 1));   // +1 self loop
}

// ---- 3-phase hierarchical exclusive scan of deg -> offsets ----

__global__ __launch_bounds__(SCAN_TPB) void k_scan_part(const int* __restrict__ deg,
                                                        int* __restrict__ partials, int n) {
    __shared__ int red[SCAN_TPB];
    int t = threadIdx.x;
    int base = blockIdx.x * SCAN_EPB + t * 8;
    int s = 0;
    if (base + 8 <= n) {
        int4 a = *(const int4*)(deg + base);
        int4 b = *(const int4*)(deg + base + 4);
        s = a.x + a.y + a.z + a.w + b.x + b.y + b.z + b.w;
    } else {
        for (int j = 0; j < 8; ++j) if (base + j < n) s += deg[base + j];
    }
    red[t] = s;
    __syncthreads();
    for (int off = SCAN_TPB / 2; off > 0; off >>= 1) {
        if (t < off) red[t] += red[t + off];
        __syncthreads();
    }
    if (t == 0) partials[blockIdx.x] = red[0];
}

__global__ __launch_bounds__(64) void k_scan_mid(int* __restrict__ partials,
                                                 int* __restrict__ offsets) {
    __shared__ int buf[SCAN_NB];
    int t = threadIdx.x;
    if (t < SCAN_NB) buf[t] = partials[t];
    __syncthreads();
    if (t == 0) {
        int run = 0;
        for (int i = 0; i < SCAN_NB; ++i) { int v = buf[i]; buf[i] = run; run += v; }
        offsets[N_NODES] = run;    // == E
    }
    __syncthreads();
    if (t < SCAN_NB) partials[t] = buf[t];
}

__global__ __launch_bounds__(SCAN_TPB) void k_scan_write(const int* __restrict__ deg,
                                                         const int* __restrict__ partials,
                                                         int* __restrict__ offsets, int n) {
    __shared__ int sums[SCAN_TPB];
    int t = threadIdx.x;
    int base = blockIdx.x * SCAN_EPB + t * 8;
    int v[8];
    if (base + 8 <= n) {
        int4 a = *(const int4*)(deg + base);
        int4 b = *(const int4*)(deg + base + 4);
        v[0] = a.x; v[1] = a.y; v[2] = a.z; v[3] = a.w;
        v[4] = b.x; v[5] = b.y; v[6] = b.z; v[7] = b.w;
    } else {
        for (int j = 0; j < 8; ++j) v[j] = (base + j < n) ? deg[base + j] : 0;
    }
    int p[8], s = 0;
#pragma unroll
    for (int j = 0; j < 8; ++j) { p[j] = s; s += v[j]; }
    sums[t] = s;
    __syncthreads();
    // Hillis-Steele inclusive scan over thread sums
    for (int off = 1; off < SCAN_TPB; off <<= 1) {
        int add = (t >= off) ? sums[t - off] : 0;
        __syncthreads();
        sums[t] += add;
        __syncthreads();
    }
    int tbase = partials[blockIdx.x] + ((t == 0) ? 0 : sums[t - 1]);
#pragma unroll
    for (int j = 0; j < 8; ++j)
        if (base + j < n) offsets[base + j] = tbase + p[j];
}

__global__ void k_fill(const int* __restrict__ row, const int* __restrict__ col,
                       const int* __restrict__ offsets, int* __restrict__ cursor,
                       const float* __restrict__ dinv,
                       int* __restrict__ srcA, float* __restrict__ wgt, int e) {
    int i = blockIdx.x * blockDim.x + threadIdx.x;
    if (i >= e) return;
    int r = row[i], c = col[i];
    int p = offsets[c] + atomicAdd(&cursor[c], 1);
    srcA[p] = r;
    wgt[p]  = dinv[r] * dinv[c];
}

// ---------------- aggregation: one wave per node, bf16 gather, 4x unroll ----------------
// z = (1-a) * (dinv_i^2 * hb[i] + sum_in norm * hb[src]) + a * h0b[i]
// residual is bf16 too: error alpha*2^-9 ~ 2e-4, negligible vs threshold.

__global__ __launch_bounds__(256) void k_agg(
        const unsigned short* __restrict__ hb,   // bf16 rows [N][128] (current h)
        const unsigned short* __restrict__ h0b,  // bf16 residual
        const int* __restrict__ offsets, const int* __restrict__ srcA,
        const float* __restrict__ wgt, const float* __restrict__ dinv,
        float* __restrict__ z, int n) {
    int wid  = (int)((blockIdx.x * (unsigned)blockDim.x + threadIdx.x) >> 6);
    int lane = threadIdx.x & 63;
    if (wid >= n) return;
    float di = dinv[wid];
    const float oma = 1.0f - ALPHA;
    int o0 = offsets[wid], o1 = offsets[wid + 1];
    ushort2 hc = ((const ushort2*)(hb  + (size_t)wid * H_DIM))[lane];
    ushort2 hz = ((const ushort2*)(h0b + (size_t)wid * H_DIM))[lane];
    float sw = oma * di * di;
    float accx = sw * bf2f(hc.x) + ALPHA * bf2f(hz.x);
    float accy = sw * bf2f(hc.y) + ALPHA * bf2f(hz.y);
    int p2 = o0;
    for (; p2 + 4 <= o1; p2 += 4) {
        int s0 = srcA[p2], s1 = srcA[p2 + 1], s2 = srcA[p2 + 2], s3 = srcA[p2 + 3];
        ushort2 g0 = ((const ushort2*)(hb + (size_t)s0 * H_DIM))[lane];
        ushort2 g1 = ((const ushort2*)(hb + (size_t)s1 * H_DIM))[lane];
        ushort2 g2 = ((const ushort2*)(hb + (size_t)s2 * H_DIM))[lane];
        ushort2 g3 = ((const ushort2*)(hb + (size_t)s3 * H_DIM))[lane];
        float w0 = oma * wgt[p2],     w1 = oma * wgt[p2 + 1];
        float w2 = oma * wgt[p2 + 2], w3 = oma * wgt[p2 + 3];
        accx += w0 * bf2f(g0.x); accy += w0 * bf2f(g0.y);
        accx += w1 * bf2f(g1.x); accy += w1 * bf2f(g1.y);
        accx += w2 * bf2f(g2.x); accy += w2 * bf2f(g2.y);
        accx += w3 * bf2f(g3.x); accy += w3 * bf2f(g3.y);
    }
    for (; p2 < o1; ++p2) {
        int s = srcA[p2];
        float wv = oma * wgt[p2];
        ushort2 g = ((const ushort2*)(hb + (size_t)s * H_DIM))[lane];
        accx += wv * bf2f(g.x); accy += wv * bf2f(g.y);
    }
    float2 o; o.x = accx; o.y = accy;
    ((float2*)(z + (size_t)wid * H_DIM))[lane] = o;
}

// ---------------- weight prep: f32 [K][N] -> bf16 hi/lo transposed [N][K] ----------------

__global__ void k_wprep(const float* __restrict__ w, unsigned short* __restrict__ hi,
                        unsigned short* __restrict__ lo, int K, int Nn) {
    int i = blockIdx.x * blockDim.x + threadIdx.x;
    if (i >= K * Nn) return;
    int n = i / K, k = i % K;
    float v = w[(size_t)k * Nn + n];
    unsigned short h = f2bf(v);
    hi[i] = h;
    lo[i] = f2bf(v - bf2f(h));
}

// ---------------- split-bf16 MFMA GEMM ----------------
// C = act(A @ B + bias); A f32 converted to hi/lo bf16 during LDS staging,
// B pre-transposed bf16 hi/lo [BN][K], cooperatively staged to LDS per K-step.
// acc += Ah*Bh + Ah*Bl + Al*Bh (~f32 accuracy). Optional f32 and/or bf16 output.
// BM=64: per-wave 32x64 output (acc 32 VGPR) -> ~110 VGPR total, fits 128-cap
// for 4 waves/SIMD; LDS 48 KB -> 3 blocks/CU (round 4: 64KB/2 blocks was the limiter).

template<int BN, bool RELU, bool BIAS, bool WF32, bool WB16>
__global__ __launch_bounds__(256, 4) void k_mfma_gemm(
        const float* __restrict__ A,
        const unsigned short* __restrict__ Bth,
        const unsigned short* __restrict__ Btl,
        const float* __restrict__ bias,
        float* __restrict__ C, unsigned short* __restrict__ Cb,
        int M, int K) {
    constexpr int BM = 64, BK = 64;
    constexpr int WN = BN / 2;       // per-wave cols (2x2 waves)
    constexpr int NF = WN / 16;      // 16x16 frags per wave in N
    __shared__ unsigned short Ah[BM * BK], Al[BM * BK];
    __shared__ unsigned short Bh[BN * BK], Bl[BN * BK];
    char* AhC = (char*)Ah; char* AlC = (char*)Al;
    char* BhC = (char*)Bh; char* BlC = (char*)Bl;
    const int tid = threadIdx.x;
    const int wave = tid >> 6, lane = tid & 63;
    const int wrow = wave >> 1, wcol = wave & 1;
    const int l15 = lane & 15, l4 = lane >> 4;
    const int bm = blockIdx.x * BM;

    f32x4 acc[2][NF];
#pragma unroll
    for (int mf = 0; mf < 2; ++mf)
#pragma unroll
        for (int nf = 0; nf < NF; ++nf) acc[mf][nf] = (f32x4){0.f, 0.f, 0.f, 0.f};

    for (int k0 = 0; k0 < K; k0 += BK) {
        // stage A: f32 -> hi/lo bf16, XOR-swizzled LDS (BM*BK/8/256 = 2 chunks)
#pragma unroll
        for (int c = 0; c < (BM * 8) / 256; ++c) {
            int ch = tid + c * 256;          // chunk = 8 elems along K
            int m = ch >> 3, kc = (ch & 7) * 8;
            int gr = bm + m;
            float v[8];
            if (gr < M) {
                const float4* src = (const float4*)(A + (size_t)gr * K + k0 + kc);
                float4 a0 = src[0], a1 = src[1];
                v[0] = a0.x; v[1] = a0.y; v[2] = a0.z; v[3] = a0.w;
                v[4] = a1.x; v[5] = a1.y; v[6] = a1.z; v[7] = a1.w;
            } else {
#pragma unroll
                for (int j = 0; j < 8; ++j) v[j] = 0.f;
            }
            bf16x8 hv, lv;
#pragma unroll
            for (int j = 0; j < 8; ++j) {
                unsigned short h = f2bf(v[j]);
                hv[j] = (short)h;
                lv[j] = (short)f2bf(v[j] - bf2f(h));
            }
            int byte = ((m * BK + kc) * 2) ^ ((m & 7) << 4);
            *(bf16x8*)(AhC + byte) = hv;
            *(bf16x8*)(AlC + byte) = lv;
        }
        // stage B (bf16 hi/lo [BN][K] row-major)
#pragma unroll
        for (int c = 0; c < (BN * 8) / 256; ++c) {
            int ch = tid + c * 256;
            int n = ch >> 3, kc = (ch & 7) * 8;
            bf16x8 hv = *(const bf16x8*)(Bth + (size_t)n * K + k0 + kc);
            bf16x8 lv = *(const bf16x8*)(Btl + (size_t)n * K + k0 + kc);
            int byte = ((n * BK + kc) * 2) ^ ((n & 7) << 4);
            *(bf16x8*)(BhC + byte) = hv;
            *(bf16x8*)(BlC + byte) = lv;
        }
        __syncthreads();
#pragma unroll
        for (int ks = 0; ks < 2; ++ks) {
            bf16x8 ah[2], al[2], bh[NF], bl[NF];
#pragma unroll
            for (int mf = 0; mf < 2; ++mf) {
                int row = wrow * 32 + mf * 16 + l15;
                int byte = ((row * BK + ks * 32 + l4 * 8) * 2) ^ ((row & 7) << 4);
                ah[mf] = *(const bf16x8*)(AhC + byte);
                al[mf] = *(const bf16x8*)(AlC + byte);
            }
#pragma unroll
            for (int nf = 0; nf < NF; ++nf) {
                int n = wcol * WN + nf * 16 + l15;
                int byte = ((n * BK + ks * 32 + l4 * 8) * 2) ^ ((n & 7) << 4);
                bh[nf] = *(const bf16x8*)(BhC + byte);
                bl[nf] = *(const bf16x8*)(BlC + byte);
            }
#pragma unroll
            for (int mf = 0; mf < 2; ++mf)
#pragma unroll
                for (int nf = 0; nf < NF; ++nf) {
                    acc[mf][nf] = __builtin_amdgcn_mfma_f32_16x16x32_bf16(ah[mf], bh[nf], acc[mf][nf], 0, 0, 0);
                    acc[mf][nf] = __builtin_amdgcn_mfma_f32_16x16x32_bf16(ah[mf], bl[nf], acc[mf][nf], 0, 0, 0);
                    acc[mf][nf] = __builtin_amdgcn_mfma_f32_16x16x32_bf16(al[mf], bh[nf], acc[mf][nf], 0, 0, 0);
                }
        }
        __syncthreads();
    }
    // epilogue: C/D layout col=lane&15, row=(lane>>4)*4+reg
#pragma unroll
    for (int mf = 0; mf < 2; ++mf) {
#pragma unroll
        for (int nf = 0; nf < NF; ++nf) {
            int col = wcol * WN + nf * 16 + l15;
            float bv = 0.f;
            if constexpr (BIAS) bv = bias[col];
#pragma unroll
            for (int r = 0; r < 4; ++r) {
                int grow = bm + wrow * 32 + mf * 16 + l4 * 4 + r;
                if (grow < M) {
                    float v = acc[mf][nf][r] + bv;
                    if constexpr (RELU) v = fmaxf(v, 0.f);
                    if constexpr (WF32) C[(size_t)grow * BN + col] = v;
                    if constexpr (WB16) Cb[(size_t)grow * BN + col] = f2bf(v);
                }
            }
        }
    }
}

// ---------------- launch ----------------

extern "C" void kernel_launch(void* const* d_in, const int* in_sizes, int n_in,
                              void* d_out, int out_size, void* d_ws, size_t ws_size,
                              hipStream_t stream) {
    const float* x  = (const float*)d_in[0];
    const int*   ei = (const int*)d_in[1];
    const float* w1 = (const float*)d_in[2];
    const float* b1 = (const float*)d_in[3];
    const float* cw = (const float*)d_in[4];
    const float* w2 = (const float*)d_in[5];
    const float* b2 = (const float*)d_in[6];
    float* out = (float*)d_out;
    const int* rowp = ei;            // source nodes
    const int* colp = ei + N_EDGES;  // target nodes

    char* p = (char*)d_ws;
    auto alloc = [&](size_t bytes) -> void* {
        void* r = (void*)p;
        p += ((bytes + 255) / 256) * 256;
        return r;
    };
    int*   deg     = (int*)  alloc((size_t)N_NODES * 4);
    int*   cursor  = (int*)  alloc((size_t)N_NODES * 4);
    int*   offsets = (int*)  alloc((size_t)(N_NODES + 1) * 4);
    int*   partials= (int*)  alloc((size_t)SCAN_NB * 4);
    int*   srcA    = (int*)  alloc((size_t)N_EDGES * 4);
    float* wgt     = (float*)alloc((size_t)N_EDGES * 4);
    float* dinv    = (float*)alloc((size_t)N_NODES * 4);
    float* z       = (float*)alloc((size_t)N_NODES * H_DIM * 4);
    unsigned short* h0b = (unsigned short*)alloc((size_t)N_NODES * H_DIM * 2);
    unsigned short* h1b = (unsigned short*)alloc((size_t)N_NODES * H_DIM * 2);
    unsigned short* w1th = (unsigned short*)alloc((size_t)H_DIM * D_IN * 2);
    unsigned short* w1tl = (unsigned short*)alloc((size_t)H_DIM * D_IN * 2);
    unsigned short* cwth = (unsigned short*)alloc((size_t)2 * H_DIM * H_DIM * 2);
    unsigned short* cwtl = (unsigned short*)alloc((size_t)2 * H_DIM * H_DIM * 2);
    unsigned short* w2th = (unsigned short*)alloc((size_t)D_OUT * H_DIM * 2);
    unsigned short* w2tl = (unsigned short*)alloc((size_t)D_OUT * H_DIM * 2);

    float* h2     = out;                              // output 0: h [N,128]
    float* logits = out + (size_t)N_NODES * H_DIM;    // output 1: [N,64]

    // CSC build
    hipLaunchKernelGGL(k_init,  dim3((N_NODES + 255) / 256), dim3(256), 0, stream, deg, cursor, N_NODES);
    hipLaunchKernelGGL(k_count, dim3((N_EDGES + 255) / 256), dim3(256), 0, stream, colp, deg, N_EDGES);
    hipLaunchKernelGGL(k_dinv,  dim3((N_NODES + 255) / 256), dim3(256), 0, stream, deg, dinv, N_NODES);
    hipLaunchKernelGGL(k_scan_part,  dim3(SCAN_NB), dim3(SCAN_TPB), 0, stream, deg, partials, N_NODES);
    hipLaunchKernelGGL(k_scan_mid,   dim3(1), dim3(64), 0, stream, partials, offsets);
    hipLaunchKernelGGL(k_scan_write, dim3(SCAN_NB), dim3(SCAN_TPB), 0, stream, deg, partials, offsets, N_NODES);
    hipLaunchKernelGGL(k_fill,  dim3((N_EDGES + 255) / 256), dim3(256), 0, stream,
                       rowp, colp, offsets, cursor, dinv, srcA, wgt, N_EDGES);

    // weight prep (tiny)
    hipLaunchKernelGGL(k_wprep, dim3((D_IN * H_DIM + 255) / 256), dim3(256), 0, stream,
                       w1, w1th, w1tl, D_IN, H_DIM);
    hipLaunchKernelGGL(k_wprep, dim3((H_DIM * H_DIM + 255) / 256), dim3(256), 0, stream,
                       cw, cwth, cwtl, H_DIM, H_DIM);
    hipLaunchKernelGGL(k_wprep, dim3((H_DIM * H_DIM + 255) / 256), dim3(256), 0, stream,
                       cw + H_DIM * H_DIM, cwth + H_DIM * H_DIM, cwtl + H_DIM * H_DIM, H_DIM, H_DIM);
    hipLaunchKernelGGL(k_wprep, dim3((H_DIM * D_OUT + 255) / 256), dim3(256), 0, stream,
                       w2, w2th, w2tl, H_DIM, D_OUT);

    int gemmGrid = (N_NODES + 63) / 64;
    // h0 = relu(x @ w1 + b1): bf16 only (residual uses bf16 too)
    hipLaunchKernelGGL((k_mfma_gemm<128, true, true, false, true>), dim3(gemmGrid), dim3(256), 0, stream,
                       x, w1th, w1tl, b1, (float*)nullptr, h0b, N_NODES, D_IN);

    int aggGrid = (int)(((size_t)N_NODES * 64 + 255) / 256);
    // layer 0
    hipLaunchKernelGGL(k_agg, dim3(aggGrid), dim3(256), 0, stream,
                       h0b, h0b, offsets, srcA, wgt, dinv, z, N_NODES);
    hipLaunchKernelGGL((k_mfma_gemm<128, false, false, false, true>), dim3(gemmGrid), dim3(256), 0, stream,
                       z, cwth, cwtl, (const float*)nullptr, (float*)nullptr, h1b, N_NODES, H_DIM);
    // layer 1
    hipLaunchKernelGGL(k_agg, dim3(aggGrid), dim3(256), 0, stream,
                       h1b, h0b, offsets, srcA, wgt, dinv, z, N_NODES);
    hipLaunchKernelGGL((k_mfma_gemm<128, false, false, true, false>), dim3(gemmGrid), dim3(256), 0, stream,
                       z, cwth + H_DIM * H_DIM, cwtl + H_DIM * H_DIM, (const float*)nullptr, h2,
                       (unsigned short*)nullptr, N_NODES, H_DIM);
    // logits = h2 @ w2 + b2
    hipLaunchKernelGGL((k_mfma_gemm<64, false, true, true, false>), dim3(gemmGrid), dim3(256), 0, stream,
                       h2, w2th, w2tl, b2, logits, (unsigned short*)nullptr, N_NODES, H_DIM);
}

// Round 8
// 478.078 us; speedup vs baseline: 1.6877x; 1.0513x over previous
//
#include <hip/hip_runtime.h>

constexpr int N_NODES = 100000;
constexpr int N_EDGES = 1600000;
constexpr int D_IN   = 512;
constexpr int H_DIM  = 128;
constexpr int D_OUT  = 64;
constexpr float ALPHA = 0.1f;

constexpr int SCAN_TPB = 256;                 // threads per scan block
constexpr int SCAN_EPB = SCAN_TPB * 8;        // 2048 elems per block
constexpr int SCAN_NB  = (N_NODES + SCAN_EPB - 1) / SCAN_EPB;   // 49

typedef __attribute__((ext_vector_type(4))) float f32x4;
typedef __attribute__((ext_vector_type(8))) short bf16x8;

__device__ __forceinline__ unsigned short f2bf(float f) {
    unsigned int u = __float_as_uint(f);
    u += 0x7fff + ((u >> 16) & 1);          // RNE
    return (unsigned short)(u >> 16);
}
__device__ __forceinline__ float bf2f(unsigned short b) {
    return __uint_as_float(((unsigned int)b) << 16);
}

// ---------------- CSC build ----------------

__global__ void k_init(int* __restrict__ deg, int n) {
    int i = blockIdx.x * blockDim.x + threadIdx.x;
    if (i < n) deg[i] = 0;
}

__global__ void k_count(const int* __restrict__ col, int* __restrict__ deg, int e) {
    int i = blockIdx.x * blockDim.x + threadIdx.x;
    if (i < e) atomicAdd(&deg[col[i]], 1);
}

__global__ void k_dinv(const int* __restrict__ deg, float* __restrict__ dinv, int n) {
    int i = blockIdx.x * blockDim.x + threadIdx.x;
    if (i < n) dinv[i] = rsqrtf((float)(deg[i] + 1));   // +1 self loop
}

// ---- 3-phase hierarchical exclusive scan of deg -> offsets (also preloads cursor) ----

__global__ __launch_bounds__(SCAN_TPB) void k_scan_part(const int* __restrict__ deg,
                                                        int* __restrict__ partials, int n) {
    __shared__ int red[SCAN_TPB];
    int t = threadIdx.x;
    int base = blockIdx.x * SCAN_EPB + t * 8;
    int s = 0;
    if (base + 8 <= n) {
        int4 a = *(const int4*)(deg + base);
        int4 b = *(const int4*)(deg + base + 4);
        s = a.x + a.y + a.z + a.w + b.x + b.y + b.z + b.w;
    } else {
        for (int j = 0; j < 8; ++j) if (base + j < n) s += deg[base + j];
    }
    red[t] = s;
    __syncthreads();
    for (int off = SCAN_TPB / 2; off > 0; off >>= 1) {
        if (t < off) red[t] += red[t + off];
        __syncthreads();
    }
    if (t == 0) partials[blockIdx.x] = red[0];
}

__global__ __launch_bounds__(64) void k_scan_mid(int* __restrict__ partials,
                                                 int* __restrict__ offsets) {
    __shared__ int buf[SCAN_NB];
    int t = threadIdx.x;
    if (t < SCAN_NB) buf[t] = partials[t];
    __syncthreads();
    if (t == 0) {
        int run = 0;
        for (int i = 0; i < SCAN_NB; ++i) { int v = buf[i]; buf[i] = run; run += v; }
        offsets[N_NODES] = run;    // == E
    }
    __syncthreads();
    if (t < SCAN_NB) partials[t] = buf[t];
}

__global__ __launch_bounds__(SCAN_TPB) void k_scan_write(const int* __restrict__ deg,
                                                         const int* __restrict__ partials,
                                                         int* __restrict__ offsets,
                                                         int* __restrict__ cursor, int n) {
    __shared__ int sums[SCAN_TPB];
    int t = threadIdx.x;
    int base = blockIdx.x * SCAN_EPB + t * 8;
    int v[8];
    if (base + 8 <= n) {
        int4 a = *(const int4*)(deg + base);
        int4 b = *(const int4*)(deg + base + 4);
        v[0] = a.x; v[1] = a.y; v[2] = a.z; v[3] = a.w;
        v[4] = b.x; v[5] = b.y; v[6] = b.z; v[7] = b.w;
    } else {
        for (int j = 0; j < 8; ++j) v[j] = (base + j < n) ? deg[base + j] : 0;
    }
    int p[8], s = 0;
#pragma unroll
    for (int j = 0; j < 8; ++j) { p[j] = s; s += v[j]; }
    sums[t] = s;
    __syncthreads();
    // Hillis-Steele inclusive scan over thread sums
    for (int off = 1; off < SCAN_TPB; off <<= 1) {
        int add = (t >= off) ? sums[t - off] : 0;
        __syncthreads();
        sums[t] += add;
        __syncthreads();
    }
    int tbase = partials[blockIdx.x] + ((t == 0) ? 0 : sums[t - 1]);
#pragma unroll
    for (int j = 0; j < 8; ++j)
        if (base + j < n) {
            int o = tbase + p[j];
            offsets[base + j] = o;
            cursor[base + j] = o;      // cursor starts at segment base: k_fill skips offsets gather
        }
}

// fill: one 8B packed scatter per edge (src node + edge weight)
__global__ void k_fill(const int* __restrict__ row, const int* __restrict__ col,
                       int* __restrict__ cursor, const float* __restrict__ dinv,
                       int2* __restrict__ edges, int e) {
    int i = blockIdx.x * blockDim.x + threadIdx.x;
    if (i >= e) return;
    int r = row[i], c = col[i];
    int p = atomicAdd(&cursor[c], 1);
    int2 v;
    v.x = r;
    v.y = __float_as_int(dinv[r] * dinv[c]);
    edges[p] = v;
}

// ---------------- aggregation: one wave per node, bf16 gather, 4x unroll ----------------
// z = (1-a) * (dinv_i^2 * hb[i] + sum_in norm * hb[src]) + a * h0b[i]

__global__ __launch_bounds__(256) void k_agg(
        const unsigned short* __restrict__ hb,   // bf16 rows [N][128] (current h)
        const unsigned short* __restrict__ h0b,  // bf16 residual
        const int* __restrict__ offsets, const int2* __restrict__ edges,
        const float* __restrict__ dinv,
        float* __restrict__ z, int n) {
    int wid  = (int)((blockIdx.x * (unsigned)blockDim.x + threadIdx.x) >> 6);
    int lane = threadIdx.x & 63;
    if (wid >= n) return;
    float di = dinv[wid];
    const float oma = 1.0f - ALPHA;
    int o0 = offsets[wid], o1 = offsets[wid + 1];
    ushort2 hc = ((const ushort2*)(hb  + (size_t)wid * H_DIM))[lane];
    ushort2 hz = ((const ushort2*)(h0b + (size_t)wid * H_DIM))[lane];
    float sw = oma * di * di;
    float accx = sw * bf2f(hc.x) + ALPHA * bf2f(hz.x);
    float accy = sw * bf2f(hc.y) + ALPHA * bf2f(hz.y);
    int p2 = o0;
    for (; p2 + 4 <= o1; p2 += 4) {
        int2 e0 = edges[p2],     e1 = edges[p2 + 1];
        int2 e2 = edges[p2 + 2], e3 = edges[p2 + 3];
        ushort2 g0 = ((const ushort2*)(hb + (size_t)e0.x * H_DIM))[lane];
        ushort2 g1 = ((const ushort2*)(hb + (size_t)e1.x * H_DIM))[lane];
        ushort2 g2 = ((const ushort2*)(hb + (size_t)e2.x * H_DIM))[lane];
        ushort2 g3 = ((const ushort2*)(hb + (size_t)e3.x * H_DIM))[lane];
        float w0 = oma * __int_as_float(e0.y), w1 = oma * __int_as_float(e1.y);
        float w2 = oma * __int_as_float(e2.y), w3 = oma * __int_as_float(e3.y);
        accx += w0 * bf2f(g0.x); accy += w0 * bf2f(g0.y);
        accx += w1 * bf2f(g1.x); accy += w1 * bf2f(g1.y);
        accx += w2 * bf2f(g2.x); accy += w2 * bf2f(g2.y);
        accx += w3 * bf2f(g3.x); accy += w3 * bf2f(g3.y);
    }
    for (; p2 < o1; ++p2) {
        int2 e = edges[p2];
        float wv = oma * __int_as_float(e.y);
        ushort2 g = ((const ushort2*)(hb + (size_t)e.x * H_DIM))[lane];
        accx += wv * bf2f(g.x); accy += wv * bf2f(g.y);
    }
    float2 o; o.x = accx; o.y = accy;
    ((float2*)(z + (size_t)wid * H_DIM))[lane] = o;
}

// ---------------- weight prep: f32 [K][N] -> bf16 hi/lo transposed [N][K] ----------------

__global__ void k_wprep(const float* __restrict__ w, unsigned short* __restrict__ hi,
                        unsigned short* __restrict__ lo, int K, int Nn) {
    int i = blockIdx.x * blockDim.x + threadIdx.x;
    if (i >= K * Nn) return;
    int n = i / K, k = i % K;
    float v = w[(size_t)k * Nn + n];
    unsigned short h = f2bf(v);
    hi[i] = h;
    lo[i] = f2bf(v - bf2f(h));
}

// ---------------- split-bf16 MFMA GEMM ----------------
// C = act(A @ B + bias); A f32 converted to hi/lo bf16 during LDS staging,
// B pre-transposed bf16 hi/lo [BN][K], cooperatively staged to LDS per K-step.
// acc += Ah*Bh + Ah*Bl + Al*Bh (~f32 accuracy). Optional f32 and/or bf16 output.
// BM=64: per-wave 32x64 (acc 32 VGPR); LDS 48 KB -> 3 blocks/CU.

template<int BN, bool RELU, bool BIAS, bool WF32, bool WB16>
__global__ __launch_bounds__(256, 4) void k_mfma_gemm(
        const float* __restrict__ A,
        const unsigned short* __restrict__ Bth,
        const unsigned short* __restrict__ Btl,
        const float* __restrict__ bias,
        float* __restrict__ C, unsigned short* __restrict__ Cb,
        int M, int K) {
    constexpr int BM = 64, BK = 64;
    constexpr int WN = BN / 2;       // per-wave cols (2x2 waves)
    constexpr int NF = WN / 16;      // 16x16 frags per wave in N
    __shared__ unsigned short Ah[BM * BK], Al[BM * BK];
    __shared__ unsigned short Bh[BN * BK], Bl[BN * BK];
    char* AhC = (char*)Ah; char* AlC = (char*)Al;
    char* BhC = (char*)Bh; char* BlC = (char*)Bl;
    const int tid = threadIdx.x;
    const int wave = tid >> 6, lane = tid & 63;
    const int wrow = wave >> 1, wcol = wave & 1;
    const int l15 = lane & 15, l4 = lane >> 4;
    const int bm = blockIdx.x * BM;

    f32x4 acc[2][NF];
#pragma unroll
    for (int mf = 0; mf < 2; ++mf)
#pragma unroll
        for (int nf = 0; nf < NF; ++nf) acc[mf][nf] = (f32x4){0.f, 0.f, 0.f, 0.f};

    for (int k0 = 0; k0 < K; k0 += BK) {
        // stage A: f32 -> hi/lo bf16, XOR-swizzled LDS (2 chunks)
#pragma unroll
        for (int c = 0; c < (BM * 8) / 256; ++c) {
            int ch = tid + c * 256;          // chunk = 8 elems along K
            int m = ch >> 3, kc = (ch & 7) * 8;
            int gr = bm + m;
            float v[8];
            if (gr < M) {
                const float4* src = (const float4*)(A + (size_t)gr * K + k0 + kc);
                float4 a0 = src[0], a1 = src[1];
                v[0] = a0.x; v[1] = a0.y; v[2] = a0.z; v[3] = a0.w;
                v[4] = a1.x; v[5] = a1.y; v[6] = a1.z; v[7] = a1.w;
            } else {
#pragma unroll
                for (int j = 0; j < 8; ++j) v[j] = 0.f;
            }
            bf16x8 hv, lv;
#pragma unroll
            for (int j = 0; j < 8; ++j) {
                unsigned short h = f2bf(v[j]);
                hv[j] = (short)h;
                lv[j] = (short)f2bf(v[j] - bf2f(h));
            }
            int byte = ((m * BK + kc) * 2) ^ ((m & 7) << 4);
            *(bf16x8*)(AhC + byte) = hv;
            *(bf16x8*)(AlC + byte) = lv;
        }
        // stage B (bf16 hi/lo [BN][K] row-major)
#pragma unroll
        for (int c = 0; c < (BN * 8) / 256; ++c) {
            int ch = tid + c * 256;
            int n = ch >> 3, kc = (ch & 7) * 8;
            bf16x8 hv = *(const bf16x8*)(Bth + (size_t)n * K + k0 + kc);
            bf16x8 lv = *(const bf16x8*)(Btl + (size_t)n * K + k0 + kc);
            int byte = ((n * BK + kc) * 2) ^ ((n & 7) << 4);
            *(bf16x8*)(BhC + byte) = hv;
            *(bf16x8*)(BlC + byte) = lv;
        }
        __syncthreads();
#pragma unroll
        for (int ks = 0; ks < 2; ++ks) {
            bf16x8 ah[2], al[2], bh[NF], bl[NF];
#pragma unroll
            for (int mf = 0; mf < 2; ++mf) {
                int row = wrow * 32 + mf * 16 + l15;
                int byte = ((row * BK + ks * 32 + l4 * 8) * 2) ^ ((row & 7) << 4);
                ah[mf] = *(const bf16x8*)(AhC + byte);
                al[mf] = *(const bf16x8*)(AlC + byte);
            }
#pragma unroll
            for (int nf = 0; nf < NF; ++nf) {
                int n = wcol * WN + nf * 16 + l15;
                int byte = ((n * BK + ks * 32 + l4 * 8) * 2) ^ ((n & 7) << 4);
                bh[nf] = *(const bf16x8*)(BhC + byte);
                bl[nf] = *(const bf16x8*)(BlC + byte);
            }
#pragma unroll
            for (int mf = 0; mf < 2; ++mf)
#pragma unroll
                for (int nf = 0; nf < NF; ++nf) {
                    acc[mf][nf] = __builtin_amdgcn_mfma_f32_16x16x32_bf16(ah[mf], bh[nf], acc[mf][nf], 0, 0, 0);
                    acc[mf][nf] = __builtin_amdgcn_mfma_f32_16x16x32_bf16(ah[mf], bl[nf], acc[mf][nf], 0, 0, 0);
                    acc[mf][nf] = __builtin_amdgcn_mfma_f32_16x16x32_bf16(al[mf], bh[nf], acc[mf][nf], 0, 0, 0);
                }
        }
        __syncthreads();
    }
    // epilogue: C/D layout col=lane&15, row=(lane>>4)*4+reg
#pragma unroll
    for (int mf = 0; mf < 2; ++mf) {
#pragma unroll
        for (int nf = 0; nf < NF; ++nf) {
            int col = wcol * WN + nf * 16 + l15;
            float bv = 0.f;
            if constexpr (BIAS) bv = bias[col];
#pragma unroll
            for (int r = 0; r < 4; ++r) {
                int grow = bm + wrow * 32 + mf * 16 + l4 * 4 + r;
                if (grow < M) {
                    float v = acc[mf][nf][r] + bv;
                    if constexpr (RELU) v = fmaxf(v, 0.f);
                    if constexpr (WF32) C[(size_t)grow * BN + col] = v;
                    if constexpr (WB16) Cb[(size_t)grow * BN + col] = f2bf(v);
                }
            }
        }
    }
}

// ---------------- launch ----------------

extern "C" void kernel_launch(void* const* d_in, const int* in_sizes, int n_in,
                              void* d_out, int out_size, void* d_ws, size_t ws_size,
                              hipStream_t stream) {
    const float* x  = (const float*)d_in[0];
    const int*   ei = (const int*)d_in[1];
    const float* w1 = (const float*)d_in[2];
    const float* b1 = (const float*)d_in[3];
    const float* cw = (const float*)d_in[4];
    const float* w2 = (const float*)d_in[5];
    const float* b2 = (const float*)d_in[6];
    float* out = (float*)d_out;
    const int* rowp = ei;            // source nodes
    const int* colp = ei + N_EDGES;  // target nodes

    char* p = (char*)d_ws;
    auto alloc = [&](size_t bytes) -> void* {
        void* r = (void*)p;
        p += ((bytes + 255) / 256) * 256;
        return r;
    };
    int*   deg     = (int*)  alloc((size_t)N_NODES * 4);
    int*   cursor  = (int*)  alloc((size_t)N_NODES * 4);
    int*   offsets = (int*)  alloc((size_t)(N_NODES + 1) * 4);
    int*   partials= (int*)  alloc((size_t)SCAN_NB * 4);
    int2*  edges   = (int2*) alloc((size_t)N_EDGES * 8);
    float* dinv    = (float*)alloc((size_t)N_NODES * 4);
    float* z       = (float*)alloc((size_t)N_NODES * H_DIM * 4);
    unsigned short* h0b = (unsigned short*)alloc((size_t)N_NODES * H_DIM * 2);
    unsigned short* h1b = (unsigned short*)alloc((size_t)N_NODES * H_DIM * 2);
    unsigned short* w1th = (unsigned short*)alloc((size_t)H_DIM * D_IN * 2);
    unsigned short* w1tl = (unsigned short*)alloc((size_t)H_DIM * D_IN * 2);
    unsigned short* cwth = (unsigned short*)alloc((size_t)2 * H_DIM * H_DIM * 2);
    unsigned short* cwtl = (unsigned short*)alloc((size_t)2 * H_DIM * H_DIM * 2);
    unsigned short* w2th = (unsigned short*)alloc((size_t)D_OUT * H_DIM * 2);
    unsigned short* w2tl = (unsigned short*)alloc((size_t)D_OUT * H_DIM * 2);

    float* h2     = out;                              // output 0: h [N,128]
    float* logits = out + (size_t)N_NODES * H_DIM;    // output 1: [N,64]

    // CSC build
    hipLaunchKernelGGL(k_init,  dim3((N_NODES + 255) / 256), dim3(256), 0, stream, deg, N_NODES);
    hipLaunchKernelGGL(k_count, dim3((N_EDGES + 255) / 256), dim3(256), 0, stream, colp, deg, N_EDGES);
    hipLaunchKernelGGL(k_dinv,  dim3((N_NODES + 255) / 256), dim3(256), 0, stream, deg, dinv, N_NODES);
    hipLaunchKernelGGL(k_scan_part,  dim3(SCAN_NB), dim3(SCAN_TPB), 0, stream, deg, partials, N_NODES);
    hipLaunchKernelGGL(k_scan_mid,   dim3(1), dim3(64), 0, stream, partials, offsets);
    hipLaunchKernelGGL(k_scan_write, dim3(SCAN_NB), dim3(SCAN_TPB), 0, stream, deg, partials, offsets, cursor, N_NODES);
    hipLaunchKernelGGL(k_fill,  dim3((N_EDGES + 255) / 256), dim3(256), 0, stream,
                       rowp, colp, cursor, dinv, edges, N_EDGES);

    // weight prep (tiny)
    hipLaunchKernelGGL(k_wprep, dim3((D_IN * H_DIM + 255) / 256), dim3(256), 0, stream,
                       w1, w1th, w1tl, D_IN, H_DIM);
    hipLaunchKernelGGL(k_wprep, dim3((H_DIM * H_DIM + 255) / 256), dim3(256), 0, stream,
                       cw, cwth, cwtl, H_DIM, H_DIM);
    hipLaunchKernelGGL(k_wprep, dim3((H_DIM * H_DIM + 255) / 256), dim3(256), 0, stream,
                       cw + H_DIM * H_DIM, cwth + H_DIM * H_DIM, cwtl + H_DIM * H_DIM, H_DIM, H_DIM);
    hipLaunchKernelGGL(k_wprep, dim3((H_DIM * D_OUT + 255) / 256), dim3(256), 0, stream,
                       w2, w2th, w2tl, H_DIM, D_OUT);

    int gemmGrid = (N_NODES + 63) / 64;
    // h0 = relu(x @ w1 + b1): bf16 only (residual uses bf16 too)
    hipLaunchKernelGGL((k_mfma_gemm<128, true, true, false, true>), dim3(gemmGrid), dim3(256), 0, stream,
                       x, w1th, w1tl, b1, (float*)nullptr, h0b, N_NODES, D_IN);

    int aggGrid = (int)(((size_t)N_NODES * 64 + 255) / 256);
    // layer 0
    hipLaunchKernelGGL(k_agg, dim3(aggGrid), dim3(256), 0, stream,
                       h0b, h0b, offsets, edges, dinv, z, N_NODES);
    hipLaunchKernelGGL((k_mfma_gemm<128, false, false, false, true>), dim3(gemmGrid), dim3(256), 0, stream,
                       z, cwth, cwtl, (const float*)nullptr, (float*)nullptr, h1b, N_NODES, H_DIM);
    // layer 1
    hipLaunchKernelGGL(k_agg, dim3(aggGrid), dim3(256), 0, stream,
                       h1b, h0b, offsets, edges, dinv, z, N_NODES);
    hipLaunchKernelGGL((k_mfma_gemm<128, false, false, true, false>), dim3(gemmGrid), dim3(256), 0, stream,
                       z, cwth + H_DIM * H_DIM, cwtl + H_DIM * H_DIM, (const float*)nullptr, h2,
                       (unsigned short*)nullptr, N_NODES, H_DIM);
    // logits = h2 @ w2 + b2
    hipLaunchKernelGGL((k_mfma_gemm<64, false, true, true, false>), dim3(gemmGrid), dim3(256), 0, stream,
                       h2, w2th, w2tl, b2, logits, (unsigned short*)nullptr, N_NODES, H_DIM);
}

// Round 9
// 445.613 us; speedup vs baseline: 1.8106x; 1.0729x over previous
//
#include <hip/hip_runtime.h>

constexpr int N_NODES = 100000;
constexpr int N_EDGES = 1600000;
constexpr int D_IN   = 512;
constexpr int H_DIM  = 128;
constexpr int D_OUT  = 64;
constexpr float ALPHA = 0.1f;

constexpr int SCAN_TPB = 256;                 // threads per scan block
constexpr int SCAN_EPB = SCAN_TPB * 8;        // 2048 elems per block
constexpr int SCAN_NB  = (N_NODES + SCAN_EPB - 1) / SCAN_EPB;   // 49

typedef __attribute__((ext_vector_type(4))) float f32x4;
typedef __attribute__((ext_vector_type(8))) short bf16x8;

__device__ __forceinline__ unsigned short f2bf(float f) {
    unsigned int u = __float_as_uint(f);
    u += 0x7fff + ((u >> 16) & 1);          // RNE
    return (unsigned short)(u >> 16);
}
__device__ __forceinline__ float bf2f(unsigned short b) {
    return __uint_as_float(((unsigned int)b) << 16);
}

// ---------------- CSC build ----------------

__global__ void k_init(int* __restrict__ deg, int n) {
    int i = blockIdx.x * blockDim.x + threadIdx.x;
    if (i < n) deg[i] = 0;
}

__global__ void k_count(const int* __restrict__ col, int* __restrict__ deg, int e) {
    int i = blockIdx.x * blockDim.x + threadIdx.x;
    if (i < e) atomicAdd(&deg[col[i]], 1);
}

__global__ void k_dinv(const int* __restrict__ deg, float* __restrict__ dinv, int n) {
    int i = blockIdx.x * blockDim.x + threadIdx.x;
    if (i < n) dinv[i] = rsqrtf((float)(deg[i] + 1));   // +1 self loop
}

// ---- 3-phase hierarchical exclusive scan of deg -> offsets (also preloads cursor) ----

__global__ __launch_bounds__(SCAN_TPB) void k_scan_part(const int* __restrict__ deg,
                                                        int* __restrict__ partials, int n) {
    __shared__ int red[SCAN_TPB];
    int t = threadIdx.x;
    int base = blockIdx.x * SCAN_EPB + t * 8;
    int s = 0;
    if (base + 8 <= n) {
        int4 a = *(const int4*)(deg + base);
        int4 b = *(const int4*)(deg + base + 4);
        s = a.x + a.y + a.z + a.w + b.x + b.y + b.z + b.w;
    } else {
        for (int j = 0; j < 8; ++j) if (base + j < n) s += deg[base + j];
    }
    red[t] = s;
    __syncthreads();
    for (int off = SCAN_TPB / 2; off > 0; off >>= 1) {
        if (t < off) red[t] += red[t + off];
        __syncthreads();
    }
    if (t == 0) partials[blockIdx.x] = red[0];
}

__global__ __launch_bounds__(64) void k_scan_mid(int* __restrict__ partials,
                                                 int* __restrict__ offsets) {
    __shared__ int buf[SCAN_NB];
    int t = threadIdx.x;
    if (t < SCAN_NB) buf[t] = partials[t];
    __syncthreads();
    if (t == 0) {
        int run = 0;
        for (int i = 0; i < SCAN_NB; ++i) { int v = buf[i]; buf[i] = run; run += v; }
        offsets[N_NODES] = run;    // == E
    }
    __syncthreads();
    if (t < SCAN_NB) partials[t] = buf[t];
}

__global__ __launch_bounds__(SCAN_TPB) void k_scan_write(const int* __restrict__ deg,
                                                         const int* __restrict__ partials,
                                                         int* __restrict__ offsets,
                                                         int* __restrict__ cursor, int n) {
    __shared__ int sums[SCAN_TPB];
    int t = threadIdx.x;
    int base = blockIdx.x * SCAN_EPB + t * 8;
    int v[8];
    if (base + 8 <= n) {
        int4 a = *(const int4*)(deg + base);
        int4 b = *(const int4*)(deg + base + 4);
        v[0] = a.x; v[1] = a.y; v[2] = a.z; v[3] = a.w;
        v[4] = b.x; v[5] = b.y; v[6] = b.z; v[7] = b.w;
    } else {
        for (int j = 0; j < 8; ++j) v[j] = (base + j < n) ? deg[base + j] : 0;
    }
    int p[8], s = 0;
#pragma unroll
    for (int j = 0; j < 8; ++j) { p[j] = s; s += v[j]; }
    sums[t] = s;
    __syncthreads();
    // Hillis-Steele inclusive scan over thread sums
    for (int off = 1; off < SCAN_TPB; off <<= 1) {
        int add = (t >= off) ? sums[t - off] : 0;
        __syncthreads();
        sums[t] += add;
        __syncthreads();
    }
    int tbase = partials[blockIdx.x] + ((t == 0) ? 0 : sums[t - 1]);
#pragma unroll
    for (int j = 0; j < 8; ++j)
        if (base + j < n) {
            int o = tbase + p[j];
            offsets[base + j] = o;
            cursor[base + j] = o;      // cursor starts at segment base: k_fill skips offsets gather
        }
}

// fill: one 8B packed scatter per edge (src node + edge weight)
__global__ void k_fill(const int* __restrict__ row, const int* __restrict__ col,
                       int* __restrict__ cursor, const float* __restrict__ dinv,
                       int2* __restrict__ edges, int e) {
    int i = blockIdx.x * blockDim.x + threadIdx.x;
    if (i >= e) return;
    int r = row[i], c = col[i];
    int p = atomicAdd(&cursor[c], 1);
    int2 v;
    v.x = r;
    v.y = __float_as_int(dinv[r] * dinv[c]);
    edges[p] = v;
}

// ---------------- aggregation: one wave per node, bf16 gather, 4x unroll ----------------
// zb = bf16( (1-a) * (dinv_i^2 * hb[i] + sum_in norm * hb[src]) + a * h0b[i] )

__global__ __launch_bounds__(256) void k_agg(
        const unsigned short* __restrict__ hb,   // bf16 rows [N][128] (current h)
        const unsigned short* __restrict__ h0b,  // bf16 residual
        const int* __restrict__ offsets, const int2* __restrict__ edges,
        const float* __restrict__ dinv,
        unsigned short* __restrict__ zb, int n) {
    int wid  = (int)((blockIdx.x * (unsigned)blockDim.x + threadIdx.x) >> 6);
    int lane = threadIdx.x & 63;
    if (wid >= n) return;
    float di = dinv[wid];
    const float oma = 1.0f - ALPHA;
    int o0 = offsets[wid], o1 = offsets[wid + 1];
    ushort2 hc = ((const ushort2*)(hb  + (size_t)wid * H_DIM))[lane];
    ushort2 hz = ((const ushort2*)(h0b + (size_t)wid * H_DIM))[lane];
    float sw = oma * di * di;
    float accx = sw * bf2f(hc.x) + ALPHA * bf2f(hz.x);
    float accy = sw * bf2f(hc.y) + ALPHA * bf2f(hz.y);
    int p2 = o0;
    for (; p2 + 4 <= o1; p2 += 4) {
        int2 e0 = edges[p2],     e1 = edges[p2 + 1];
        int2 e2 = edges[p2 + 2], e3 = edges[p2 + 3];
        ushort2 g0 = ((const ushort2*)(hb + (size_t)e0.x * H_DIM))[lane];
        ushort2 g1 = ((const ushort2*)(hb + (size_t)e1.x * H_DIM))[lane];
        ushort2 g2 = ((const ushort2*)(hb + (size_t)e2.x * H_DIM))[lane];
        ushort2 g3 = ((const ushort2*)(hb + (size_t)e3.x * H_DIM))[lane];
        float w0 = oma * __int_as_float(e0.y), w1 = oma * __int_as_float(e1.y);
        float w2 = oma * __int_as_float(e2.y), w3 = oma * __int_as_float(e3.y);
        accx += w0 * bf2f(g0.x); accy += w0 * bf2f(g0.y);
        accx += w1 * bf2f(g1.x); accy += w1 * bf2f(g1.y);
        accx += w2 * bf2f(g2.x); accy += w2 * bf2f(g2.y);
        accx += w3 * bf2f(g3.x); accy += w3 * bf2f(g3.y);
    }
    for (; p2 < o1; ++p2) {
        int2 e = edges[p2];
        float wv = oma * __int_as_float(e.y);
        ushort2 g = ((const ushort2*)(hb + (size_t)e.x * H_DIM))[lane];
        accx += wv * bf2f(g.x); accy += wv * bf2f(g.y);
    }
    ushort2 o; o.x = f2bf(accx); o.y = f2bf(accy);
    ((ushort2*)(zb + (size_t)wid * H_DIM))[lane] = o;
}

// ---------------- weight prep: f32 [K][N] -> bf16 hi/lo transposed [N][K] ----------------

__global__ void k_wprep(const float* __restrict__ w, unsigned short* __restrict__ hi,
                        unsigned short* __restrict__ lo, int K, int Nn) {
    int i = blockIdx.x * blockDim.x + threadIdx.x;
    if (i >= K * Nn) return;
    int n = i / K, k = i % K;
    float v = w[(size_t)k * Nn + n];
    unsigned short h = f2bf(v);
    hi[i] = h;
    lo[i] = f2bf(v - bf2f(h));
}

// ---------------- bf16-activation MFMA GEMM ----------------
// C = act(A @ B + bias); A = bf16(activations) — either converted from f32 during
// staging (AF32) or already bf16 (zb path, straight 16B copies). B stays f32-accurate
// via hi/lo split: acc += Ah*Bh + Ah*Bl (2 MFMA, effective A=bf16(A), B=f32).
// LDS 40 KB (Ah 8 + Bh 16 + Bl 16) -> 4 blocks/CU at (256,4); VGPR ~105, no spill.

template<int BN, bool AF32, bool RELU, bool BIAS, bool WF32, bool WB16>
__global__ __launch_bounds__(256, 4) void k_mfma_gemm(
        const float* __restrict__ Af,
        const unsigned short* __restrict__ Ab,
        const unsigned short* __restrict__ Bth,
        const unsigned short* __restrict__ Btl,
        const float* __restrict__ bias,
        float* __restrict__ C, unsigned short* __restrict__ Cb,
        int M, int K) {
    constexpr int BM = 64, BK = 64;
    constexpr int WN = BN / 2;       // per-wave cols (2x2 waves)
    constexpr int NF = WN / 16;      // 16x16 frags per wave in N
    __shared__ unsigned short Ah[BM * BK];
    __shared__ unsigned short Bh[BN * BK], Bl[BN * BK];
    char* AhC = (char*)Ah;
    char* BhC = (char*)Bh; char* BlC = (char*)Bl;
    const int tid = threadIdx.x;
    const int wave = tid >> 6, lane = tid & 63;
    const int wrow = wave >> 1, wcol = wave & 1;
    const int l15 = lane & 15, l4 = lane >> 4;
    const int bm = blockIdx.x * BM;

    f32x4 acc[2][NF];
#pragma unroll
    for (int mf = 0; mf < 2; ++mf)
#pragma unroll
        for (int nf = 0; nf < NF; ++nf) acc[mf][nf] = (f32x4){0.f, 0.f, 0.f, 0.f};

    for (int k0 = 0; k0 < K; k0 += BK) {
        // stage A into XOR-swizzled LDS (2 chunks of 8 K-elems per thread)
#pragma unroll
        for (int c = 0; c < (BM * 8) / 256; ++c) {
            int ch = tid + c * 256;
            int m = ch >> 3, kc = (ch & 7) * 8;
            int gr = bm + m;
            bf16x8 hv;
            if constexpr (AF32) {
                float v[8];
                if (gr < M) {
                    const float4* src = (const float4*)(Af + (size_t)gr * K + k0 + kc);
                    float4 a0 = src[0], a1 = src[1];
                    v[0] = a0.x; v[1] = a0.y; v[2] = a0.z; v[3] = a0.w;
                    v[4] = a1.x; v[5] = a1.y; v[6] = a1.z; v[7] = a1.w;
                } else {
#pragma unroll
                    for (int j = 0; j < 8; ++j) v[j] = 0.f;
                }
#pragma unroll
                for (int j = 0; j < 8; ++j) hv[j] = (short)f2bf(v[j]);
            } else {
                if (gr < M) {
                    hv = *(const bf16x8*)(Ab + (size_t)gr * K + k0 + kc);
                } else {
                    hv = (bf16x8){0, 0, 0, 0, 0, 0, 0, 0};
                }
            }
            int byte = ((m * BK + kc) * 2) ^ ((m & 7) << 4);
            *(bf16x8*)(AhC + byte) = hv;
        }
        // stage B (bf16 hi/lo [BN][K] row-major)
#pragma unroll
        for (int c = 0; c < (BN * 8) / 256; ++c) {
            int ch = tid + c * 256;
            int n = ch >> 3, kc = (ch & 7) * 8;
            bf16x8 hv = *(const bf16x8*)(Bth + (size_t)n * K + k0 + kc);
            bf16x8 lv = *(const bf16x8*)(Btl + (size_t)n * K + k0 + kc);
            int byte = ((n * BK + kc) * 2) ^ ((n & 7) << 4);
            *(bf16x8*)(BhC + byte) = hv;
            *(bf16x8*)(BlC + byte) = lv;
        }
        __syncthreads();
#pragma unroll
        for (int ks = 0; ks < 2; ++ks) {
            bf16x8 ah[2], bh[NF], bl[NF];
#pragma unroll
            for (int mf = 0; mf < 2; ++mf) {
                int row = wrow * 32 + mf * 16 + l15;
                int byte = ((row * BK + ks * 32 + l4 * 8) * 2) ^ ((row & 7) << 4);
                ah[mf] = *(const bf16x8*)(AhC + byte);
            }
#pragma unroll
            for (int nf = 0; nf < NF; ++nf) {
                int n = wcol * WN + nf * 16 + l15;
                int byte = ((n * BK + ks * 32 + l4 * 8) * 2) ^ ((n & 7) << 4);
                bh[nf] = *(const bf16x8*)(BhC + byte);
                bl[nf] = *(const bf16x8*)(BlC + byte);
            }
#pragma unroll
            for (int mf = 0; mf < 2; ++mf)
#pragma unroll
                for (int nf = 0; nf < NF; ++nf) {
                    acc[mf][nf] = __builtin_amdgcn_mfma_f32_16x16x32_bf16(ah[mf], bh[nf], acc[mf][nf], 0, 0, 0);
                    acc[mf][nf] = __builtin_amdgcn_mfma_f32_16x16x32_bf16(ah[mf], bl[nf], acc[mf][nf], 0, 0, 0);
                }
        }
        __syncthreads();
    }
    // epilogue: C/D layout col=lane&15, row=(lane>>4)*4+reg
#pragma unroll
    for (int mf = 0; mf < 2; ++mf) {
#pragma unroll
        for (int nf = 0; nf < NF; ++nf) {
            int col = wcol * WN + nf * 16 + l15;
            float bv = 0.f;
            if constexpr (BIAS) bv = bias[col];
#pragma unroll
            for (int r = 0; r < 4; ++r) {
                int grow = bm + wrow * 32 + mf * 16 + l4 * 4 + r;
                if (grow < M) {
                    float v = acc[mf][nf][r] + bv;
                    if constexpr (RELU) v = fmaxf(v, 0.f);
                    if constexpr (WF32) C[(size_t)grow * BN + col] = v;
                    if constexpr (WB16) Cb[(size_t)grow * BN + col] = f2bf(v);
                }
            }
        }
    }
}

// ---------------- launch ----------------

extern "C" void kernel_launch(void* const* d_in, const int* in_sizes, int n_in,
                              void* d_out, int out_size, void* d_ws, size_t ws_size,
                              hipStream_t stream) {
    const float* x  = (const float*)d_in[0];
    const int*   ei = (const int*)d_in[1];
    const float* w1 = (const float*)d_in[2];
    const float* b1 = (const float*)d_in[3];
    const float* cw = (const float*)d_in[4];
    const float* w2 = (const float*)d_in[5];
    const float* b2 = (const float*)d_in[6];
    float* out = (float*)d_out;
    const int* rowp = ei;            // source nodes
    const int* colp = ei + N_EDGES;  // target nodes

    char* p = (char*)d_ws;
    auto alloc = [&](size_t bytes) -> void* {
        void* r = (void*)p;
        p += ((bytes + 255) / 256) * 256;
        return r;
    };
    int*   deg     = (int*)  alloc((size_t)N_NODES * 4);
    int*   cursor  = (int*)  alloc((size_t)N_NODES * 4);
    int*   offsets = (int*)  alloc((size_t)(N_NODES + 1) * 4);
    int*   partials= (int*)  alloc((size_t)SCAN_NB * 4);
    int2*  edges   = (int2*) alloc((size_t)N_EDGES * 8);
    float* dinv    = (float*)alloc((size_t)N_NODES * 4);
    unsigned short* zb  = (unsigned short*)alloc((size_t)N_NODES * H_DIM * 2);
    unsigned short* h0b = (unsigned short*)alloc((size_t)N_NODES * H_DIM * 2);
    unsigned short* h1b = (unsigned short*)alloc((size_t)N_NODES * H_DIM * 2);
    unsigned short* w1th = (unsigned short*)alloc((size_t)H_DIM * D_IN * 2);
    unsigned short* w1tl = (unsigned short*)alloc((size_t)H_DIM * D_IN * 2);
    unsigned short* cwth = (unsigned short*)alloc((size_t)2 * H_DIM * H_DIM * 2);
    unsigned short* cwtl = (unsigned short*)alloc((size_t)2 * H_DIM * H_DIM * 2);
    unsigned short* w2th = (unsigned short*)alloc((size_t)D_OUT * H_DIM * 2);
    unsigned short* w2tl = (unsigned short*)alloc((size_t)D_OUT * H_DIM * 2);

    float* h2     = out;                              // output 0: h [N,128]
    float* logits = out + (size_t)N_NODES * H_DIM;    // output 1: [N,64]

    // CSC build
    hipLaunchKernelGGL(k_init,  dim3((N_NODES + 255) / 256), dim3(256), 0, stream, deg, N_NODES);
    hipLaunchKernelGGL(k_count, dim3((N_EDGES + 255) / 256), dim3(256), 0, stream, colp, deg, N_EDGES);
    hipLaunchKernelGGL(k_dinv,  dim3((N_NODES + 255) / 256), dim3(256), 0, stream, deg, dinv, N_NODES);
    hipLaunchKernelGGL(k_scan_part,  dim3(SCAN_NB), dim3(SCAN_TPB), 0, stream, deg, partials, N_NODES);
    hipLaunchKernelGGL(k_scan_mid,   dim3(1), dim3(64), 0, stream, partials, offsets);
    hipLaunchKernelGGL(k_scan_write, dim3(SCAN_NB), dim3(SCAN_TPB), 0, stream, deg, partials, offsets, cursor, N_NODES);
    hipLaunchKernelGGL(k_fill,  dim3((N_EDGES + 255) / 256), dim3(256), 0, stream,
                       rowp, colp, cursor, dinv, edges, N_EDGES);

    // weight prep (tiny)
    hipLaunchKernelGGL(k_wprep, dim3((D_IN * H_DIM + 255) / 256), dim3(256), 0, stream,
                       w1, w1th, w1tl, D_IN, H_DIM);
    hipLaunchKernelGGL(k_wprep, dim3((H_DIM * H_DIM + 255) / 256), dim3(256), 0, stream,
                       cw, cwth, cwtl, H_DIM, H_DIM);
    hipLaunchKernelGGL(k_wprep, dim3((H_DIM * H_DIM + 255) / 256), dim3(256), 0, stream,
                       cw + H_DIM * H_DIM, cwth + H_DIM * H_DIM, cwtl + H_DIM * H_DIM, H_DIM, H_DIM);
    hipLaunchKernelGGL(k_wprep, dim3((H_DIM * D_OUT + 255) / 256), dim3(256), 0, stream,
                       w2, w2th, w2tl, H_DIM, D_OUT);

    int gemmGrid = (N_NODES + 63) / 64;
    // h0 = relu(x @ w1 + b1): bf16 (AF32 staging converts x)
    hipLaunchKernelGGL((k_mfma_gemm<128, true, true, true, false, true>), dim3(gemmGrid), dim3(256), 0, stream,
                       x, (const unsigned short*)nullptr, w1th, w1tl, b1,
                       (float*)nullptr, h0b, N_NODES, D_IN);

    int aggGrid = (int)(((size_t)N_NODES * 64 + 255) / 256);
    // layer 0
    hipLaunchKernelGGL(k_agg, dim3(aggGrid), dim3(256), 0, stream,
                       h0b, h0b, offsets, edges, dinv, zb, N_NODES);
    hipLaunchKernelGGL((k_mfma_gemm<128, false, false, false, false, true>), dim3(gemmGrid), dim3(256), 0, stream,
                       (const float*)nullptr, zb, cwth, cwtl, (const float*)nullptr,
                       (float*)nullptr, h1b, N_NODES, H_DIM);
    // layer 1
    hipLaunchKernelGGL(k_agg, dim3(aggGrid), dim3(256), 0, stream,
                       h1b, h0b, offsets, edges, dinv, zb, N_NODES);
    hipLaunchKernelGGL((k_mfma_gemm<128, false, false, false, true, false>), dim3(gemmGrid), dim3(256), 0, stream,
                       (const float*)nullptr, zb, cwth + H_DIM * H_DIM, cwtl + H_DIM * H_DIM,
                       (const float*)nullptr, h2, (unsigned short*)nullptr, N_NODES, H_DIM);
    // logits = h2 @ w2 + b2 (A = h2 f32)
    hipLaunchKernelGGL((k_mfma_gemm<64, true, false, true, true, false>), dim3(gemmGrid), dim3(256), 0, stream,
                       h2, (const unsigned short*)nullptr, w2th, w2tl, b2,
                       logits, (unsigned short*)nullptr, N_NODES, H_DIM);
}

// Round 10
// 438.775 us; speedup vs baseline: 1.8389x; 1.0156x over previous
//
#include <hip/hip_runtime.h>

constexpr int N_NODES = 100000;
constexpr int N_EDGES = 1600000;
constexpr int D_IN   = 512;
constexpr int H_DIM  = 128;
constexpr int D_OUT  = 64;
constexpr float ALPHA = 0.1f;

constexpr int SCAN_TPB = 256;                 // threads per scan block
constexpr int SCAN_EPB = SCAN_TPB * 8;        // 2048 elems per block
constexpr int SCAN_NB  = (N_NODES + SCAN_EPB - 1) / SCAN_EPB;   // 49

typedef __attribute__((ext_vector_type(4))) float f32x4;
typedef __attribute__((ext_vector_type(8))) short bf16x8;

__device__ __forceinline__ unsigned short f2bf(float f) {
    unsigned int u = __float_as_uint(f);
    u += 0x7fff + ((u >> 16) & 1);          // RNE
    return (unsigned short)(u >> 16);
}
__device__ __forceinline__ float bf2f(unsigned short b) {
    return __uint_as_float(((unsigned int)b) << 16);
}

// ---------------- CSC build ----------------

__global__ void k_init(int* __restrict__ deg, int n) {
    int i = blockIdx.x * blockDim.x + threadIdx.x;
    if (i < n) deg[i] = 0;
}

__global__ void k_count(const int* __restrict__ col, int* __restrict__ deg, int e) {
    int i = blockIdx.x * blockDim.x + threadIdx.x;
    if (i < e) atomicAdd(&deg[col[i]], 1);
}

// ---- 3-phase hierarchical exclusive scan of deg -> offsets (+cursor preload, +dinv) ----

__global__ __launch_bounds__(SCAN_TPB) void k_scan_part(const int* __restrict__ deg,
                                                        int* __restrict__ partials, int n) {
    __shared__ int red[SCAN_TPB];
    int t = threadIdx.x;
    int base = blockIdx.x * SCAN_EPB + t * 8;
    int s = 0;
    if (base + 8 <= n) {
        int4 a = *(const int4*)(deg + base);
        int4 b = *(const int4*)(deg + base + 4);
        s = a.x + a.y + a.z + a.w + b.x + b.y + b.z + b.w;
    } else {
        for (int j = 0; j < 8; ++j) if (base + j < n) s += deg[base + j];
    }
    red[t] = s;
    __syncthreads();
    for (int off = SCAN_TPB / 2; off > 0; off >>= 1) {
        if (t < off) red[t] += red[t + off];
        __syncthreads();
    }
    if (t == 0) partials[blockIdx.x] = red[0];
}

__global__ __launch_bounds__(64) void k_scan_mid(int* __restrict__ partials,
                                                 int* __restrict__ offsets) {
    __shared__ int buf[SCAN_NB];
    int t = threadIdx.x;
    if (t < SCAN_NB) buf[t] = partials[t];
    __syncthreads();
    if (t == 0) {
        int run = 0;
        for (int i = 0; i < SCAN_NB; ++i) { int v = buf[i]; buf[i] = run; run += v; }
        offsets[N_NODES] = run;    // == E
    }
    __syncthreads();
    if (t < SCAN_NB) partials[t] = buf[t];
}

__global__ __launch_bounds__(SCAN_TPB) void k_scan_write(const int* __restrict__ deg,
                                                         const int* __restrict__ partials,
                                                         int* __restrict__ offsets,
                                                         int* __restrict__ cursor,
                                                         float* __restrict__ dinv, int n) {
    __shared__ int sums[SCAN_TPB];
    int t = threadIdx.x;
    int base = blockIdx.x * SCAN_EPB + t * 8;
    int v[8];
    if (base + 8 <= n) {
        int4 a = *(const int4*)(deg + base);
        int4 b = *(const int4*)(deg + base + 4);
        v[0] = a.x; v[1] = a.y; v[2] = a.z; v[3] = a.w;
        v[4] = b.x; v[5] = b.y; v[6] = b.z; v[7] = b.w;
    } else {
        for (int j = 0; j < 8; ++j) v[j] = (base + j < n) ? deg[base + j] : 0;
    }
    int p[8], s = 0;
#pragma unroll
    for (int j = 0; j < 8; ++j) { p[j] = s; s += v[j]; }
    sums[t] = s;
    __syncthreads();
    for (int off = 1; off < SCAN_TPB; off <<= 1) {
        int add = (t >= off) ? sums[t - off] : 0;
        __syncthreads();
        sums[t] += add;
        __syncthreads();
    }
    int tbase = partials[blockIdx.x] + ((t == 0) ? 0 : sums[t - 1]);
#pragma unroll
    for (int j = 0; j < 8; ++j)
        if (base + j < n) {
            int o = tbase + p[j];
            offsets[base + j] = o;
            cursor[base + j] = o;                       // k_fill skips offsets gather
            dinv[base + j] = rsqrtf((float)(v[j] + 1)); // fused k_dinv (+1 self loop)
        }
}

// fill: one 8B packed scatter per edge (src node + edge weight)
__global__ void k_fill(const int* __restrict__ row, const int* __restrict__ col,
                       int* __restrict__ cursor, const float* __restrict__ dinv,
                       int2* __restrict__ edges, int e) {
    int i = blockIdx.x * blockDim.x + threadIdx.x;
    if (i >= e) return;
    int r = row[i], c = col[i];
    int p = atomicAdd(&cursor[c], 1);
    int2 v;
    v.x = r;
    v.y = __float_as_int(dinv[r] * dinv[c]);
    edges[p] = v;
}

// ---------------- aggregation: one wave per node, bf16 gather, 8x unroll ----------------
// zb = bf16( (1-a) * (dinv_i^2 * hb[i] + sum_in norm * hb[src]) + a * h0b[i] )

__global__ __launch_bounds__(256) void k_agg(
        const unsigned short* __restrict__ hb,   // bf16 rows [N][128] (current h)
        const unsigned short* __restrict__ h0b,  // bf16 residual
        const int* __restrict__ offsets, const int2* __restrict__ edges,
        const float* __restrict__ dinv,
        unsigned short* __restrict__ zb, int n) {
    int wid  = (int)((blockIdx.x * (unsigned)blockDim.x + threadIdx.x) >> 6);
    int lane = threadIdx.x & 63;
    if (wid >= n) return;
    float di = dinv[wid];
    const float oma = 1.0f - ALPHA;
    int o0 = offsets[wid], o1 = offsets[wid + 1];
    ushort2 hc = ((const ushort2*)(hb  + (size_t)wid * H_DIM))[lane];
    ushort2 hz = ((const ushort2*)(h0b + (size_t)wid * H_DIM))[lane];
    float sw = oma * di * di;
    float accx = sw * bf2f(hc.x) + ALPHA * bf2f(hz.x);
    float accy = sw * bf2f(hc.y) + ALPHA * bf2f(hz.y);
    int p2 = o0;
    for (; p2 + 8 <= o1; p2 += 8) {
        int2 e[8];
        ushort2 g[8];
#pragma unroll
        for (int j = 0; j < 8; ++j) e[j] = edges[p2 + j];
#pragma unroll
        for (int j = 0; j < 8; ++j)
            g[j] = ((const ushort2*)(hb + (size_t)e[j].x * H_DIM))[lane];
#pragma unroll
        for (int j = 0; j < 8; ++j) {
            float w = oma * __int_as_float(e[j].y);
            accx += w * bf2f(g[j].x);
            accy += w * bf2f(g[j].y);
        }
    }
    for (; p2 < o1; ++p2) {
        int2 e = edges[p2];
        float wv = oma * __int_as_float(e.y);
        ushort2 g = ((const ushort2*)(hb + (size_t)e.x * H_DIM))[lane];
        accx += wv * bf2f(g.x); accy += wv * bf2f(g.y);
    }
    ushort2 o; o.x = f2bf(accx); o.y = f2bf(accy);
    ((ushort2*)(zb + (size_t)wid * H_DIM))[lane] = o;
}

// ---------------- fused weight prep: all 3 weights, f32 [K][N] -> bf16 hi/lo [N][K] ----------------

constexpr int W1_E = D_IN * H_DIM;            // 65536
constexpr int CW_E = 2 * H_DIM * H_DIM;       // 32768
constexpr int W2_E = H_DIM * D_OUT;           // 8192

__global__ void k_wprep_all(const float* __restrict__ w1, const float* __restrict__ cw,
                            const float* __restrict__ w2,
                            unsigned short* __restrict__ w1th, unsigned short* __restrict__ w1tl,
                            unsigned short* __restrict__ cwth, unsigned short* __restrict__ cwtl,
                            unsigned short* __restrict__ w2th, unsigned short* __restrict__ w2tl) {
    int i = blockIdx.x * blockDim.x + threadIdx.x;
    const float* src; unsigned short *dh, *dl; int K, Nn, j;
    if (i < W1_E) {
        src = w1; dh = w1th; dl = w1tl; K = D_IN; Nn = H_DIM; j = i;
    } else if (i < W1_E + CW_E) {
        j = i - W1_E; int l = j >> 14; j &= 16383;
        src = cw + l * H_DIM * H_DIM; dh = cwth + l * H_DIM * H_DIM; dl = cwtl + l * H_DIM * H_DIM;
        K = H_DIM; Nn = H_DIM;
    } else if (i < W1_E + CW_E + W2_E) {
        j = i - W1_E - CW_E; src = w2; dh = w2th; dl = w2tl; K = H_DIM; Nn = D_OUT;
    } else return;
    int n = j / K, k = j % K;
    float v = src[(size_t)k * Nn + n];
    unsigned short h = f2bf(v);
    dh[j] = h;
    dl[j] = f2bf(v - bf2f(h));
}

// ---------------- bf16-activation MFMA GEMM ----------------
// C = act(A @ B + bias); A bf16 (AF32: converted from f32 during staging).
// B f32-accurate via hi/lo: acc += Ah*Bh + Ah*Bl (2 MFMA).
// LDS 40 KB -> 4 blocks/CU at (256,4); VGPR ~105.

template<int BN, bool AF32, bool RELU, bool BIAS, bool WF32, bool WB16>
__global__ __launch_bounds__(256, 4) void k_mfma_gemm(
        const float* __restrict__ Af,
        const unsigned short* __restrict__ Ab,
        const unsigned short* __restrict__ Bth,
        const unsigned short* __restrict__ Btl,
        const float* __restrict__ bias,
        float* __restrict__ C, unsigned short* __restrict__ Cb,
        int M, int K) {
    constexpr int BM = 64, BK = 64;
    constexpr int WN = BN / 2;
    constexpr int NF = WN / 16;
    __shared__ unsigned short Ah[BM * BK];
    __shared__ unsigned short Bh[BN * BK], Bl[BN * BK];
    char* AhC = (char*)Ah;
    char* BhC = (char*)Bh; char* BlC = (char*)Bl;
    const int tid = threadIdx.x;
    const int wave = tid >> 6, lane = tid & 63;
    const int wrow = wave >> 1, wcol = wave & 1;
    const int l15 = lane & 15, l4 = lane >> 4;
    const int bm = blockIdx.x * BM;

    f32x4 acc[2][NF];
#pragma unroll
    for (int mf = 0; mf < 2; ++mf)
#pragma unroll
        for (int nf = 0; nf < NF; ++nf) acc[mf][nf] = (f32x4){0.f, 0.f, 0.f, 0.f};

    for (int k0 = 0; k0 < K; k0 += BK) {
#pragma unroll
        for (int c = 0; c < (BM * 8) / 256; ++c) {
            int ch = tid + c * 256;
            int m = ch >> 3, kc = (ch & 7) * 8;
            int gr = bm + m;
            bf16x8 hv;
            if constexpr (AF32) {
                float v[8];
                if (gr < M) {
                    const float4* src = (const float4*)(Af + (size_t)gr * K + k0 + kc);
                    float4 a0 = src[0], a1 = src[1];
                    v[0] = a0.x; v[1] = a0.y; v[2] = a0.z; v[3] = a0.w;
                    v[4] = a1.x; v[5] = a1.y; v[6] = a1.z; v[7] = a1.w;
                } else {
#pragma unroll
                    for (int j = 0; j < 8; ++j) v[j] = 0.f;
                }
#pragma unroll
                for (int j = 0; j < 8; ++j) hv[j] = (short)f2bf(v[j]);
            } else {
                if (gr < M) {
                    hv = *(const bf16x8*)(Ab + (size_t)gr * K + k0 + kc);
                } else {
                    hv = (bf16x8){0, 0, 0, 0, 0, 0, 0, 0};
                }
            }
            int byte = ((m * BK + kc) * 2) ^ ((m & 7) << 4);
            *(bf16x8*)(AhC + byte) = hv;
        }
#pragma unroll
        for (int c = 0; c < (BN * 8) / 256; ++c) {
            int ch = tid + c * 256;
            int n = ch >> 3, kc = (ch & 7) * 8;
            bf16x8 hv = *(const bf16x8*)(Bth + (size_t)n * K + k0 + kc);
            bf16x8 lv = *(const bf16x8*)(Btl + (size_t)n * K + k0 + kc);
            int byte = ((n * BK + kc) * 2) ^ ((n & 7) << 4);
            *(bf16x8*)(BhC + byte) = hv;
            *(bf16x8*)(BlC + byte) = lv;
        }
        __syncthreads();
#pragma unroll
        for (int ks = 0; ks < 2; ++ks) {
            bf16x8 ah[2], bh[NF], bl[NF];
#pragma unroll
            for (int mf = 0; mf < 2; ++mf) {
                int row = wrow * 32 + mf * 16 + l15;
                int byte = ((row * BK + ks * 32 + l4 * 8) * 2) ^ ((row & 7) << 4);
                ah[mf] = *(const bf16x8*)(AhC + byte);
            }
#pragma unroll
            for (int nf = 0; nf < NF; ++nf) {
                int n = wcol * WN + nf * 16 + l15;
                int byte = ((n * BK + ks * 32 + l4 * 8) * 2) ^ ((n & 7) << 4);
                bh[nf] = *(const bf16x8*)(BhC + byte);
                bl[nf] = *(const bf16x8*)(BlC + byte);
            }
#pragma unroll
            for (int mf = 0; mf < 2; ++mf)
#pragma unroll
                for (int nf = 0; nf < NF; ++nf) {
                    acc[mf][nf] = __builtin_amdgcn_mfma_f32_16x16x32_bf16(ah[mf], bh[nf], acc[mf][nf], 0, 0, 0);
                    acc[mf][nf] = __builtin_amdgcn_mfma_f32_16x16x32_bf16(ah[mf], bl[nf], acc[mf][nf], 0, 0, 0);
                }
        }
        __syncthreads();
    }
#pragma unroll
    for (int mf = 0; mf < 2; ++mf) {
#pragma unroll
        for (int nf = 0; nf < NF; ++nf) {
            int col = wcol * WN + nf * 16 + l15;
            float bv = 0.f;
            if constexpr (BIAS) bv = bias[col];
#pragma unroll
            for (int r = 0; r < 4; ++r) {
                int grow = bm + wrow * 32 + mf * 16 + l4 * 4 + r;
                if (grow < M) {
                    float v = acc[mf][nf][r] + bv;
                    if constexpr (RELU) v = fmaxf(v, 0.f);
                    if constexpr (WF32) C[(size_t)grow * BN + col] = v;
                    if constexpr (WB16) Cb[(size_t)grow * BN + col] = f2bf(v);
                }
            }
        }
    }
}

// ---------------- fused conv-layer-1 + logits kernel ----------------
// Phase 1: h2_tile = zb @ cw1 (K=128, BN=128), write h2 f32 to d_out, stash bf16(h2) in LDS.
// Phase 2: logits_tile = bf16(h2_tile) @ w2(hi/lo) + b2 (K=128, BN2=64).
// Numerics identical to the previous separate kernels (logits A was bf16(h2) there too).
// LDS 48 KB (phase1: Ah 8K | Bh 16K | Bl 16K; phase2 overlay: A2 16K | W2h 16K | W2l 16K).

__global__ __launch_bounds__(256, 3) void k_conv1_logits(
        const unsigned short* __restrict__ Ab,     // zb [M][128]
        const unsigned short* __restrict__ Bth,    // cw1 hi [128][128]
        const unsigned short* __restrict__ Btl,    // cw1 lo
        const unsigned short* __restrict__ W2h,    // w2 hi [64][128]
        const unsigned short* __restrict__ W2l,    // w2 lo
        const float* __restrict__ b2,
        float* __restrict__ h2, float* __restrict__ logits, int M) {
    constexpr int BM = 64, BK = 64, BN = 128, K = 128;
    constexpr int WN = BN / 2, NF = WN / 16;
    __shared__ char lds[49152];
    char* AhC = lds;                 // phase1 A: [64][64] bf16, 8 KB
    char* BhC = lds + 8192;          // phase1 B hi: [128][64], 16 KB
    char* BlC = lds + 24576;         // phase1 B lo: [128][64], 16 KB
    char* A2C = lds;                 // phase2 A: [64][128] bf16, 16 KB (overlays Ah+Bh[0:8K])
    char* WhC = lds + 16384;         // phase2 w2 hi: [64][128], 16 KB
    char* WlC = lds + 32768;         // phase2 w2 lo: [64][128], 16 KB
    const int tid = threadIdx.x;
    const int wave = tid >> 6, lane = tid & 63;
    const int wrow = wave >> 1, wcol = wave & 1;
    const int l15 = lane & 15, l4 = lane >> 4;
    const int bm = blockIdx.x * BM;

    // ---- phase 1: conv GEMM (identical math to k_mfma_gemm<128,false,...>) ----
    f32x4 acc[2][NF];
#pragma unroll
    for (int mf = 0; mf < 2; ++mf)
#pragma unroll
        for (int nf = 0; nf < NF; ++nf) acc[mf][nf] = (f32x4){0.f, 0.f, 0.f, 0.f};

    for (int k0 = 0; k0 < K; k0 += BK) {
#pragma unroll
        for (int c = 0; c < (BM * 8) / 256; ++c) {
            int ch = tid + c * 256;
            int m = ch >> 3, kc = (ch & 7) * 8;
            int gr = bm + m;
            bf16x8 hv;
            if (gr < M) hv = *(const bf16x8*)(Ab + (size_t)gr * K + k0 + kc);
            else        hv = (bf16x8){0, 0, 0, 0, 0, 0, 0, 0};
            int byte = ((m * BK + kc) * 2) ^ ((m & 7) << 4);
            *(bf16x8*)(AhC + byte) = hv;
        }
#pragma unroll
        for (int c = 0; c < (BN * 8) / 256; ++c) {
            int ch = tid + c * 256;
            int n = ch >> 3, kc = (ch & 7) * 8;
            bf16x8 hv = *(const bf16x8*)(Bth + (size_t)n * K + k0 + kc);
            bf16x8 lv = *(const bf16x8*)(Btl + (size_t)n * K + k0 + kc);
            int byte = ((n * BK + kc) * 2) ^ ((n & 7) << 4);
            *(bf16x8*)(BhC + byte) = hv;
            *(bf16x8*)(BlC + byte) = lv;
        }
        __syncthreads();
#pragma unroll
        for (int ks = 0; ks < 2; ++ks) {
            bf16x8 ah[2], bh[NF], bl[NF];
#pragma unroll
            for (int mf = 0; mf < 2; ++mf) {
                int row = wrow * 32 + mf * 16 + l15;
                int byte = ((row * BK + ks * 32 + l4 * 8) * 2) ^ ((row & 7) << 4);
                ah[mf] = *(const bf16x8*)(AhC + byte);
            }
#pragma unroll
            for (int nf = 0; nf < NF; ++nf) {
                int n = wcol * WN + nf * 16 + l15;
                int byte = ((n * BK + ks * 32 + l4 * 8) * 2) ^ ((n & 7) << 4);
                bh[nf] = *(const bf16x8*)(BhC + byte);
                bl[nf] = *(const bf16x8*)(BlC + byte);
            }
#pragma unroll
            for (int mf = 0; mf < 2; ++mf)
#pragma unroll
                for (int nf = 0; nf < NF; ++nf) {
                    acc[mf][nf] = __builtin_amdgcn_mfma_f32_16x16x32_bf16(ah[mf], bh[nf], acc[mf][nf], 0, 0, 0);
                    acc[mf][nf] = __builtin_amdgcn_mfma_f32_16x16x32_bf16(ah[mf], bl[nf], acc[mf][nf], 0, 0, 0);
                }
        }
        __syncthreads();
    }
    // epilogue: write h2 f32 (global) + bf16 h2 tile to LDS A2 [64][128] swizzled
#pragma unroll
    for (int mf = 0; mf < 2; ++mf) {
#pragma unroll
        for (int nf = 0; nf < NF; ++nf) {
            int col = wcol * WN + nf * 16 + l15;
#pragma unroll
            for (int r = 0; r < 4; ++r) {
                int mrow = wrow * 32 + mf * 16 + l4 * 4 + r;
                int grow = bm + mrow;
                float v = acc[mf][nf][r];
                if (grow < M) h2[(size_t)grow * BN + col] = v;
                int byte = ((mrow * 128 + col) * 2) ^ ((mrow & 7) << 4);
                *(unsigned short*)(A2C + byte) = f2bf(v);
            }
        }
    }
    // stage w2 hi/lo [64][128] into LDS (regions disjoint from A2)
#pragma unroll
    for (int c = 0; c < 4; ++c) {       // 8192 elems / 8 / 256 = 4 chunks
        int ch = tid + c * 256;
        int n = ch >> 4, kc = (ch & 15) * 8;
        bf16x8 hv = *(const bf16x8*)(W2h + (size_t)n * 128 + kc);
        bf16x8 lv = *(const bf16x8*)(W2l + (size_t)n * 128 + kc);
        int byte = ((n * 128 + kc) * 2) ^ ((n & 7) << 4);
        *(bf16x8*)(WhC + byte) = hv;
        *(bf16x8*)(WlC + byte) = lv;
    }
    __syncthreads();

    // ---- phase 2: logits = A2 @ w2 + b2 (BN2=64; per wave 32x32) ----
    f32x4 acc2[2][2];
#pragma unroll
    for (int mf = 0; mf < 2; ++mf)
#pragma unroll
        for (int nf = 0; nf < 2; ++nf) acc2[mf][nf] = (f32x4){0.f, 0.f, 0.f, 0.f};
#pragma unroll
    for (int ks = 0; ks < 4; ++ks) {
        bf16x8 a2[2], wh[2], wl[2];
#pragma unroll
        for (int mf = 0; mf < 2; ++mf) {
            int row = wrow * 32 + mf * 16 + l15;
            int byte = ((row * 128 + ks * 32 + l4 * 8) * 2) ^ ((row & 7) << 4);
            a2[mf] = *(const bf16x8*)(A2C + byte);
        }
#pragma unroll
        for (int nf = 0; nf < 2; ++nf) {
            int n = wcol * 32 + nf * 16 + l15;
            int byte = ((n * 128 + ks * 32 + l4 * 8) * 2) ^ ((n & 7) << 4);
            wh[nf] = *(const bf16x8*)(WhC + byte);
            wl[nf] = *(const bf16x8*)(WlC + byte);
        }
#pragma unroll
        for (int mf = 0; mf < 2; ++mf)
#pragma unroll
            for (int nf = 0; nf < 2; ++nf) {
                acc2[mf][nf] = __builtin_amdgcn_mfma_f32_16x16x32_bf16(a2[mf], wh[nf], acc2[mf][nf], 0, 0, 0);
                acc2[mf][nf] = __builtin_amdgcn_mfma_f32_16x16x32_bf16(a2[mf], wl[nf], acc2[mf][nf], 0, 0, 0);
            }
    }
#pragma unroll
    for (int mf = 0; mf < 2; ++mf) {
#pragma unroll
        for (int nf = 0; nf < 2; ++nf) {
            int col = wcol * 32 + nf * 16 + l15;
            float bv = b2[col];
#pragma unroll
            for (int r = 0; r < 4; ++r) {
                int grow = bm + wrow * 32 + mf * 16 + l4 * 4 + r;
                if (grow < M)
                    logits[(size_t)grow * D_OUT + col] = acc2[mf][nf][r] + bv;
            }
        }
    }
}

// ---------------- launch ----------------

extern "C" void kernel_launch(void* const* d_in, const int* in_sizes, int n_in,
                              void* d_out, int out_size, void* d_ws, size_t ws_size,
                              hipStream_t stream) {
    const float* x  = (const float*)d_in[0];
    const int*   ei = (const int*)d_in[1];
    const float* w1 = (const float*)d_in[2];
    const float* b1 = (const float*)d_in[3];
    const float* cw = (const float*)d_in[4];
    const float* w2 = (const float*)d_in[5];
    const float* b2 = (const float*)d_in[6];
    float* out = (float*)d_out;
    const int* rowp = ei;            // source nodes
    const int* colp = ei + N_EDGES;  // target nodes

    char* p = (char*)d_ws;
    auto alloc = [&](size_t bytes) -> void* {
        void* r = (void*)p;
        p += ((bytes + 255) / 256) * 256;
        return r;
    };
    int*   deg     = (int*)  alloc((size_t)N_NODES * 4);
    int*   cursor  = (int*)  alloc((size_t)N_NODES * 4);
    int*   offsets = (int*)  alloc((size_t)(N_NODES + 1) * 4);
    int*   partials= (int*)  alloc((size_t)SCAN_NB * 4);
    int2*  edges   = (int2*) alloc((size_t)N_EDGES * 8);
    float* dinv    = (float*)alloc((size_t)N_NODES * 4);
    unsigned short* zb  = (unsigned short*)alloc((size_t)N_NODES * H_DIM * 2);
    unsigned short* h0b = (unsigned short*)alloc((size_t)N_NODES * H_DIM * 2);
    unsigned short* h1b = (unsigned short*)alloc((size_t)N_NODES * H_DIM * 2);
    unsigned short* w1th = (unsigned short*)alloc((size_t)W1_E * 2);
    unsigned short* w1tl = (unsigned short*)alloc((size_t)W1_E * 2);
    unsigned short* cwth = (unsigned short*)alloc((size_t)CW_E * 2);
    unsigned short* cwtl = (unsigned short*)alloc((size_t)CW_E * 2);
    unsigned short* w2th = (unsigned short*)alloc((size_t)W2_E * 2);
    unsigned short* w2tl = (unsigned short*)alloc((size_t)W2_E * 2);

    float* h2     = out;                              // output 0: h [N,128]
    float* logits = out + (size_t)N_NODES * H_DIM;    // output 1: [N,64]

    // CSC build
    hipLaunchKernelGGL(k_init,  dim3((N_NODES + 255) / 256), dim3(256), 0, stream, deg, N_NODES);
    hipLaunchKernelGGL(k_count, dim3((N_EDGES + 255) / 256), dim3(256), 0, stream, colp, deg, N_EDGES);
    hipLaunchKernelGGL(k_scan_part,  dim3(SCAN_NB), dim3(SCAN_TPB), 0, stream, deg, partials, N_NODES);
    hipLaunchKernelGGL(k_scan_mid,   dim3(1), dim3(64), 0, stream, partials, offsets);
    hipLaunchKernelGGL(k_scan_write, dim3(SCAN_NB), dim3(SCAN_TPB), 0, stream,
                       deg, partials, offsets, cursor, dinv, N_NODES);
    hipLaunchKernelGGL(k_fill,  dim3((N_EDGES + 255) / 256), dim3(256), 0, stream,
                       rowp, colp, cursor, dinv, edges, N_EDGES);

    // weight prep (single kernel)
    hipLaunchKernelGGL(k_wprep_all, dim3((W1_E + CW_E + W2_E + 255) / 256), dim3(256), 0, stream,
                       w1, cw, w2, w1th, w1tl, cwth, cwtl, w2th, w2tl);

    int gemmGrid = (N_NODES + 63) / 64;
    // h0 = relu(x @ w1 + b1): bf16 (AF32 staging converts x)
    hipLaunchKernelGGL((k_mfma_gemm<128, true, true, true, false, true>), dim3(gemmGrid), dim3(256), 0, stream,
                       x, (const unsigned short*)nullptr, w1th, w1tl, b1,
                       (float*)nullptr, h0b, N_NODES, D_IN);

    int aggGrid = (int)(((size_t)N_NODES * 64 + 255) / 256);
    // layer 0
    hipLaunchKernelGGL(k_agg, dim3(aggGrid), dim3(256), 0, stream,
                       h0b, h0b, offsets, edges, dinv, zb, N_NODES);
    hipLaunchKernelGGL((k_mfma_gemm<128, false, false, false, false, true>), dim3(gemmGrid), dim3(256), 0, stream,
                       (const float*)nullptr, zb, cwth, cwtl, (const float*)nullptr,
                       (float*)nullptr, h1b, N_NODES, H_DIM);
    // layer 1
    hipLaunchKernelGGL(k_agg, dim3(aggGrid), dim3(256), 0, stream,
                       h1b, h0b, offsets, edges, dinv, zb, N_NODES);
    // conv1 + logits fused
    hipLaunchKernelGGL(k_conv1_logits, dim3(gemmGrid), dim3(256), 0, stream,
                       zb, cwth + H_DIM * H_DIM, cwtl + H_DIM * H_DIM,
                       w2th, w2tl, b2, h2, logits, N_NODES);
}

// Round 11
// 414.887 us; speedup vs baseline: 1.9447x; 1.0576x over previous
//
#include <hip/hip_runtime.h>

constexpr int N_NODES = 100000;
constexpr int N_EDGES = 1600000;
constexpr int D_IN   = 512;
constexpr int H_DIM  = 128;
constexpr int D_OUT  = 64;
constexpr float ALPHA = 0.1f;

constexpr int SCAN_TPB = 256;                 // threads per scan block
constexpr int SCAN_EPB = SCAN_TPB * 8;        // 2048 elems per block
constexpr int SCAN_NB  = (N_NODES + SCAN_EPB - 1) / SCAN_EPB;   // 49

typedef __attribute__((ext_vector_type(4))) float f32x4;
typedef __attribute__((ext_vector_type(8))) short bf16x8;

__device__ __forceinline__ unsigned short f2bf(float f) {
    unsigned int u = __float_as_uint(f);
    u += 0x7fff + ((u >> 16) & 1);          // RNE
    return (unsigned short)(u >> 16);
}
__device__ __forceinline__ float bf2f(unsigned short b) {
    return __uint_as_float(((unsigned int)b) << 16);
}

// ---------------- CSC build ----------------

__global__ void k_init(int* __restrict__ deg, int n) {
    int i = blockIdx.x * blockDim.x + threadIdx.x;
    if (i < n) deg[i] = 0;
}

// ---- fused weight prep bodies ----

constexpr int W1_E = D_IN * H_DIM;            // 65536
constexpr int CW_E = 2 * H_DIM * H_DIM;       // 32768
constexpr int W2_E = H_DIM * D_OUT;           // 8192
constexpr int WP_E = W1_E + CW_E + W2_E;      // 106496
constexpr int WP_NB = (WP_E + 255) / 256;     // 416

__device__ __forceinline__ void wprep_body(int i,
        const float* __restrict__ w1, const float* __restrict__ cw,
        const float* __restrict__ w2,
        unsigned short* __restrict__ w1th, unsigned short* __restrict__ w1tl,
        unsigned short* __restrict__ cwth, unsigned short* __restrict__ cwtl,
        unsigned short* __restrict__ w2th, unsigned short* __restrict__ w2tl) {
    const float* src; unsigned short *dh, *dl; int K, Nn, j;
    if (i < W1_E) {
        src = w1; dh = w1th; dl = w1tl; K = D_IN; Nn = H_DIM; j = i;
    } else if (i < W1_E + CW_E) {
        j = i - W1_E; int l = j >> 14; j &= 16383;
        src = cw + l * H_DIM * H_DIM; dh = cwth + l * H_DIM * H_DIM; dl = cwtl + l * H_DIM * H_DIM;
        K = H_DIM; Nn = H_DIM;
    } else if (i < WP_E) {
        j = i - W1_E - CW_E; src = w2; dh = w2th; dl = w2tl; K = H_DIM; Nn = D_OUT;
    } else return;
    int n = j / K, k = j % K;
    float v = src[(size_t)k * Nn + n];
    unsigned short h = f2bf(v);
    dh[j] = h;
    dl[j] = f2bf(v - bf2f(h));
}

// MEGA_A: degree count (family 0) + weight prep (family 1)
constexpr int CNT_NB = (N_EDGES + 255) / 256;   // 6250

__global__ __launch_bounds__(256) void k_mega_count_wprep(
        const int* __restrict__ col, int* __restrict__ deg,
        const float* __restrict__ w1, const float* __restrict__ cw, const float* __restrict__ w2,
        unsigned short* __restrict__ w1th, unsigned short* __restrict__ w1tl,
        unsigned short* __restrict__ cwth, unsigned short* __restrict__ cwtl,
        unsigned short* __restrict__ w2th, unsigned short* __restrict__ w2tl) {
    int b = blockIdx.x;
    if (b < CNT_NB) {
        int i = b * 256 + threadIdx.x;
        if (i < N_EDGES) atomicAdd(&deg[col[i]], 1);
    } else {
        int i = (b - CNT_NB) * 256 + threadIdx.x;
        wprep_body(i, w1, cw, w2, w1th, w1tl, cwth, cwtl, w2th, w2tl);
    }
}

// ---- 3-phase hierarchical exclusive scan of deg -> offsets (+cursor preload, +dinv) ----

__global__ __launch_bounds__(SCAN_TPB) void k_scan_part(const int* __restrict__ deg,
                                                        int* __restrict__ partials, int n) {
    __shared__ int red[SCAN_TPB];
    int t = threadIdx.x;
    int base = blockIdx.x * SCAN_EPB + t * 8;
    int s = 0;
    if (base + 8 <= n) {
        int4 a = *(const int4*)(deg + base);
        int4 b = *(const int4*)(deg + base + 4);
        s = a.x + a.y + a.z + a.w + b.x + b.y + b.z + b.w;
    } else {
        for (int j = 0; j < 8; ++j) if (base + j < n) s += deg[base + j];
    }
    red[t] = s;
    __syncthreads();
    for (int off = SCAN_TPB / 2; off > 0; off >>= 1) {
        if (t < off) red[t] += red[t + off];
        __syncthreads();
    }
    if (t == 0) partials[blockIdx.x] = red[0];
}

__global__ __launch_bounds__(64) void k_scan_mid(int* __restrict__ partials,
                                                 int* __restrict__ offsets) {
    __shared__ int buf[SCAN_NB];
    int t = threadIdx.x;
    if (t < SCAN_NB) buf[t] = partials[t];
    __syncthreads();
    if (t == 0) {
        int run = 0;
        for (int i = 0; i < SCAN_NB; ++i) { int v = buf[i]; buf[i] = run; run += v; }
        offsets[N_NODES] = run;    // == E
    }
    __syncthreads();
    if (t < SCAN_NB) partials[t] = buf[t];
}

__global__ __launch_bounds__(SCAN_TPB) void k_scan_write(const int* __restrict__ deg,
                                                         const int* __restrict__ partials,
                                                         int* __restrict__ offsets,
                                                         int* __restrict__ cursor,
                                                         float* __restrict__ dinv, int n) {
    __shared__ int sums[SCAN_TPB];
    int t = threadIdx.x;
    int base = blockIdx.x * SCAN_EPB + t * 8;
    int v[8];
    if (base + 8 <= n) {
        int4 a = *(const int4*)(deg + base);
        int4 b = *(const int4*)(deg + base + 4);
        v[0] = a.x; v[1] = a.y; v[2] = a.z; v[3] = a.w;
        v[4] = b.x; v[5] = b.y; v[6] = b.z; v[7] = b.w;
    } else {
        for (int j = 0; j < 8; ++j) v[j] = (base + j < n) ? deg[base + j] : 0;
    }
    int p[8], s = 0;
#pragma unroll
    for (int j = 0; j < 8; ++j) { p[j] = s; s += v[j]; }
    sums[t] = s;
    __syncthreads();
    for (int off = 1; off < SCAN_TPB; off <<= 1) {
        int add = (t >= off) ? sums[t - off] : 0;
        __syncthreads();
        sums[t] += add;
        __syncthreads();
    }
    int tbase = partials[blockIdx.x] + ((t == 0) ? 0 : sums[t - 1]);
#pragma unroll
    for (int j = 0; j < 8; ++j)
        if (base + j < n) {
            int o = tbase + p[j];
            offsets[base + j] = o;
            cursor[base + j] = o;                       // k_fill skips offsets gather
            dinv[base + j] = rsqrtf((float)(v[j] + 1)); // fused k_dinv (+1 self loop)
        }
}

// ---------------- aggregation: one wave per node, bf16 gather, 8x unroll ----------------
// zb = bf16( (1-a) * (dinv_i^2 * hb[i] + sum_in norm * hb[src]) + a * h0b[i] )

__global__ __launch_bounds__(256) void k_agg(
        const unsigned short* __restrict__ hb,   // bf16 rows [N][128] (current h)
        const unsigned short* __restrict__ h0b,  // bf16 residual
        const int* __restrict__ offsets, const int2* __restrict__ edges,
        const float* __restrict__ dinv,
        unsigned short* __restrict__ zb, int n) {
    int wid  = (int)((blockIdx.x * (unsigned)blockDim.x + threadIdx.x) >> 6);
    int lane = threadIdx.x & 63;
    if (wid >= n) return;
    float di = dinv[wid];
    const float oma = 1.0f - ALPHA;
    int o0 = offsets[wid], o1 = offsets[wid + 1];
    ushort2 hc = ((const ushort2*)(hb  + (size_t)wid * H_DIM))[lane];
    ushort2 hz = ((const ushort2*)(h0b + (size_t)wid * H_DIM))[lane];
    float sw = oma * di * di;
    float accx = sw * bf2f(hc.x) + ALPHA * bf2f(hz.x);
    float accy = sw * bf2f(hc.y) + ALPHA * bf2f(hz.y);
    int p2 = o0;
    for (; p2 + 8 <= o1; p2 += 8) {
        int2 e[8];
        ushort2 g[8];
#pragma unroll
        for (int j = 0; j < 8; ++j) e[j] = edges[p2 + j];
#pragma unroll
        for (int j = 0; j < 8; ++j)
            g[j] = ((const ushort2*)(hb + (size_t)e[j].x * H_DIM))[lane];
#pragma unroll
        for (int j = 0; j < 8; ++j) {
            float w = oma * __int_as_float(e[j].y);
            accx += w * bf2f(g[j].x);
            accy += w * bf2f(g[j].y);
        }
    }
    for (; p2 < o1; ++p2) {
        int2 e = edges[p2];
        float wv = oma * __int_as_float(e.y);
        ushort2 g = ((const ushort2*)(hb + (size_t)e.x * H_DIM))[lane];
        accx += wv * bf2f(g.x); accy += wv * bf2f(g.y);
    }
    ushort2 o; o.x = f2bf(accx); o.y = f2bf(accy);
    ((ushort2*)(zb + (size_t)wid * H_DIM))[lane] = o;
}

// ---------------- bf16-activation MFMA GEMM body (shared) ----------------
// C = act(A @ B + bias); A bf16 (AF32: converted from f32 during staging).
// B f32-accurate via hi/lo: acc += Ah*Bh + Ah*Bl (2 MFMA).

template<int BN, bool AF32, bool RELU, bool BIAS, bool WF32, bool WB16>
__device__ __forceinline__ void gemm_body(
        char* AhC, char* BhC, char* BlC, int bm, int tid,
        const float* __restrict__ Af,
        const unsigned short* __restrict__ Ab,
        const unsigned short* __restrict__ Bth,
        const unsigned short* __restrict__ Btl,
        const float* __restrict__ bias,
        float* __restrict__ C, unsigned short* __restrict__ Cb,
        int M, int K) {
    constexpr int BM = 64, BK = 64;
    constexpr int WN = BN / 2;
    constexpr int NF = WN / 16;
    const int wave = tid >> 6, lane = tid & 63;
    const int wrow = wave >> 1, wcol = wave & 1;
    const int l15 = lane & 15, l4 = lane >> 4;

    f32x4 acc[2][NF];
#pragma unroll
    for (int mf = 0; mf < 2; ++mf)
#pragma unroll
        for (int nf = 0; nf < NF; ++nf) acc[mf][nf] = (f32x4){0.f, 0.f, 0.f, 0.f};

    for (int k0 = 0; k0 < K; k0 += BK) {
#pragma unroll
        for (int c = 0; c < (BM * 8) / 256; ++c) {
            int ch = tid + c * 256;
            int m = ch >> 3, kc = (ch & 7) * 8;
            int gr = bm + m;
            bf16x8 hv;
            if constexpr (AF32) {
                float v[8];
                if (gr < M) {
                    const float4* src = (const float4*)(Af + (size_t)gr * K + k0 + kc);
                    float4 a0 = src[0], a1 = src[1];
                    v[0] = a0.x; v[1] = a0.y; v[2] = a0.z; v[3] = a0.w;
                    v[4] = a1.x; v[5] = a1.y; v[6] = a1.z; v[7] = a1.w;
                } else {
#pragma unroll
                    for (int j = 0; j < 8; ++j) v[j] = 0.f;
                }
#pragma unroll
                for (int j = 0; j < 8; ++j) hv[j] = (short)f2bf(v[j]);
            } else {
                if (gr < M) {
                    hv = *(const bf16x8*)(Ab + (size_t)gr * K + k0 + kc);
                } else {
                    hv = (bf16x8){0, 0, 0, 0, 0, 0, 0, 0};
                }
            }
            int byte = ((m * BK + kc) * 2) ^ ((m & 7) << 4);
            *(bf16x8*)(AhC + byte) = hv;
        }
#pragma unroll
        for (int c = 0; c < (BN * 8) / 256; ++c) {
            int ch = tid + c * 256;
            int n = ch >> 3, kc = (ch & 7) * 8;
            bf16x8 hv = *(const bf16x8*)(Bth + (size_t)n * K + k0 + kc);
            bf16x8 lv = *(const bf16x8*)(Btl + (size_t)n * K + k0 + kc);
            int byte = ((n * BK + kc) * 2) ^ ((n & 7) << 4);
            *(bf16x8*)(BhC + byte) = hv;
            *(bf16x8*)(BlC + byte) = lv;
        }
        __syncthreads();
#pragma unroll
        for (int ks = 0; ks < 2; ++ks) {
            bf16x8 ah[2], bh[NF], bl[NF];
#pragma unroll
            for (int mf = 0; mf < 2; ++mf) {
                int row = wrow * 32 + mf * 16 + l15;
                int byte = ((row * BK + ks * 32 + l4 * 8) * 2) ^ ((row & 7) << 4);
                ah[mf] = *(const bf16x8*)(AhC + byte);
            }
#pragma unroll
            for (int nf = 0; nf < NF; ++nf) {
                int n = wcol * WN + nf * 16 + l15;
                int byte = ((n * BK + ks * 32 + l4 * 8) * 2) ^ ((n & 7) << 4);
                bh[nf] = *(const bf16x8*)(BhC + byte);
                bl[nf] = *(const bf16x8*)(BlC + byte);
            }
#pragma unroll
            for (int mf = 0; mf < 2; ++mf)
#pragma unroll
                for (int nf = 0; nf < NF; ++nf) {
                    acc[mf][nf] = __builtin_amdgcn_mfma_f32_16x16x32_bf16(ah[mf], bh[nf], acc[mf][nf], 0, 0, 0);
                    acc[mf][nf] = __builtin_amdgcn_mfma_f32_16x16x32_bf16(ah[mf], bl[nf], acc[mf][nf], 0, 0, 0);
                }
        }
        __syncthreads();
    }
#pragma unroll
    for (int mf = 0; mf < 2; ++mf) {
#pragma unroll
        for (int nf = 0; nf < NF; ++nf) {
            int col = wcol * WN + nf * 16 + l15;
            float bv = 0.f;
            if constexpr (BIAS) bv = bias[col];
#pragma unroll
            for (int r = 0; r < 4; ++r) {
                int grow = bm + wrow * 32 + mf * 16 + l4 * 4 + r;
                if (grow < M) {
                    float v = acc[mf][nf][r] + bv;
                    if constexpr (RELU) v = fmaxf(v, 0.f);
                    if constexpr (WF32) C[(size_t)grow * BN + col] = v;
                    if constexpr (WB16) Cb[(size_t)grow * BN + col] = f2bf(v);
                }
            }
        }
    }
}

// plain GEMM kernel (conv layer 0)
template<int BN, bool AF32, bool RELU, bool BIAS, bool WF32, bool WB16>
__global__ __launch_bounds__(256, 4) void k_mfma_gemm(
        const float* __restrict__ Af,
        const unsigned short* __restrict__ Ab,
        const unsigned short* __restrict__ Bth,
        const unsigned short* __restrict__ Btl,
        const float* __restrict__ bias,
        float* __restrict__ C, unsigned short* __restrict__ Cb,
        int M, int K) {
    __shared__ char lds[(64 + 2 * BN) * 64 * 2];
    gemm_body<BN, AF32, RELU, BIAS, WF32, WB16>(
        lds, lds + 64 * 64 * 2, lds + (64 + BN) * 64 * 2,
        blockIdx.x * 64, threadIdx.x, Af, Ab, Bth, Btl, bias, C, Cb, M, K);
}

// MEGA_B: edge fill (family 0, 4-of-5 blocks) + lin1 GEMM (family 1, 1-of-5 blocks).
// Independent stages co-scheduled so fill's scatter stalls hide under lin1's MFMA+HBM reads.
constexpr int LIN1_NB = (N_NODES + 63) / 64;                 // 1563
constexpr int MEGA_B_NB = LIN1_NB * 5;                        // 7815 (fill: 6252 slots for 6250)

__global__ __launch_bounds__(256, 4) void k_mega_fill_lin1(
        const int* __restrict__ row, const int* __restrict__ col,
        int* __restrict__ cursor, const float* __restrict__ dinv,
        int2* __restrict__ edges,
        const float* __restrict__ x,
        const unsigned short* __restrict__ w1th, const unsigned short* __restrict__ w1tl,
        const float* __restrict__ b1, unsigned short* __restrict__ h0b) {
    __shared__ char lds[(64 + 2 * 128) * 64 * 2];   // 40 KB (gemm family)
    int b = blockIdx.x;
    if ((b % 5) == 4) {
        // lin1: h0b = bf16(relu(x @ w1 + b1))
        gemm_body<128, true, true, true, false, true>(
            lds, lds + 64 * 64 * 2, lds + (64 + 128) * 64 * 2,
            (b / 5) * 64, threadIdx.x, x, nullptr, w1th, w1tl, b1,
            nullptr, h0b, N_NODES, D_IN);
    } else {
        int fidx = (b / 5) * 4 + (b % 5);
        int i = fidx * 256 + (int)threadIdx.x;
        if (i < N_EDGES) {
            int r = row[i], c = col[i];
            int p = atomicAdd(&cursor[c], 1);
            int2 v;
            v.x = r;
            v.y = __float_as_int(dinv[r] * dinv[c]);
            edges[p] = v;
        }
    }
}

// ---------------- fused conv-layer-1 + logits kernel ----------------

__global__ __launch_bounds__(256, 3) void k_conv1_logits(
        const unsigned short* __restrict__ Ab,     // zb [M][128]
        const unsigned short* __restrict__ Bth,    // cw1 hi [128][128]
        const unsigned short* __restrict__ Btl,    // cw1 lo
        const unsigned short* __restrict__ W2h,    // w2 hi [64][128]
        const unsigned short* __restrict__ W2l,    // w2 lo
        const float* __restrict__ b2,
        float* __restrict__ h2, float* __restrict__ logits, int M) {
    constexpr int BM = 64, BK = 64, BN = 128, K = 128;
    constexpr int WN = BN / 2, NF = WN / 16;
    __shared__ char lds[49152];
    char* AhC = lds;                 // phase1 A: [64][64] bf16, 8 KB
    char* BhC = lds + 8192;          // phase1 B hi: [128][64], 16 KB
    char* BlC = lds + 24576;         // phase1 B lo: [128][64], 16 KB
    char* A2C = lds;                 // phase2 A: [64][128] bf16, 16 KB
    char* WhC = lds + 16384;         // phase2 w2 hi: [64][128], 16 KB
    char* WlC = lds + 32768;         // phase2 w2 lo: [64][128], 16 KB
    const int tid = threadIdx.x;
    const int wave = tid >> 6, lane = tid & 63;
    const int wrow = wave >> 1, wcol = wave & 1;
    const int l15 = lane & 15, l4 = lane >> 4;
    const int bm = blockIdx.x * BM;

    f32x4 acc[2][NF];
#pragma unroll
    for (int mf = 0; mf < 2; ++mf)
#pragma unroll
        for (int nf = 0; nf < NF; ++nf) acc[mf][nf] = (f32x4){0.f, 0.f, 0.f, 0.f};

    for (int k0 = 0; k0 < K; k0 += BK) {
#pragma unroll
        for (int c = 0; c < (BM * 8) / 256; ++c) {
            int ch = tid + c * 256;
            int m = ch >> 3, kc = (ch & 7) * 8;
            int gr = bm + m;
            bf16x8 hv;
            if (gr < M) hv = *(const bf16x8*)(Ab + (size_t)gr * K + k0 + kc);
            else        hv = (bf16x8){0, 0, 0, 0, 0, 0, 0, 0};
            int byte = ((m * BK + kc) * 2) ^ ((m & 7) << 4);
            *(bf16x8*)(AhC + byte) = hv;
        }
#pragma unroll
        for (int c = 0; c < (BN * 8) / 256; ++c) {
            int ch = tid + c * 256;
            int n = ch >> 3, kc = (ch & 7) * 8;
            bf16x8 hv = *(const bf16x8*)(Bth + (size_t)n * K + k0 + kc);
            bf16x8 lv = *(const bf16x8*)(Btl + (size_t)n * K + k0 + kc);
            int byte = ((n * BK + kc) * 2) ^ ((n & 7) << 4);
            *(bf16x8*)(BhC + byte) = hv;
            *(bf16x8*)(BlC + byte) = lv;
        }
        __syncthreads();
#pragma unroll
        for (int ks = 0; ks < 2; ++ks) {
            bf16x8 ah[2], bh[NF], bl[NF];
#pragma unroll
            for (int mf = 0; mf < 2; ++mf) {
                int row = wrow * 32 + mf * 16 + l15;
                int byte = ((row * BK + ks * 32 + l4 * 8) * 2) ^ ((row & 7) << 4);
                ah[mf] = *(const bf16x8*)(AhC + byte);
            }
#pragma unroll
            for (int nf = 0; nf < NF; ++nf) {
                int n = wcol * WN + nf * 16 + l15;
                int byte = ((n * BK + ks * 32 + l4 * 8) * 2) ^ ((n & 7) << 4);
                bh[nf] = *(const bf16x8*)(BhC + byte);
                bl[nf] = *(const bf16x8*)(BlC + byte);
            }
#pragma unroll
            for (int mf = 0; mf < 2; ++mf)
#pragma unroll
                for (int nf = 0; nf < NF; ++nf) {
                    acc[mf][nf] = __builtin_amdgcn_mfma_f32_16x16x32_bf16(ah[mf], bh[nf], acc[mf][nf], 0, 0, 0);
                    acc[mf][nf] = __builtin_amdgcn_mfma_f32_16x16x32_bf16(ah[mf], bl[nf], acc[mf][nf], 0, 0, 0);
                }
        }
        __syncthreads();
    }
    // epilogue: write h2 f32 (global) + bf16 h2 tile to LDS A2 [64][128] swizzled
#pragma unroll
    for (int mf = 0; mf < 2; ++mf) {
#pragma unroll
        for (int nf = 0; nf < NF; ++nf) {
            int col = wcol * WN + nf * 16 + l15;
#pragma unroll
            for (int r = 0; r < 4; ++r) {
                int mrow = wrow * 32 + mf * 16 + l4 * 4 + r;
                int grow = bm + mrow;
                float v = acc[mf][nf][r];
                if (grow < M) h2[(size_t)grow * BN + col] = v;
                int byte = ((mrow * 128 + col) * 2) ^ ((mrow & 7) << 4);
                *(unsigned short*)(A2C + byte) = f2bf(v);
            }
        }
    }
    // stage w2 hi/lo [64][128] into LDS
#pragma unroll
    for (int c = 0; c < 4; ++c) {
        int ch = tid + c * 256;
        int n = ch >> 4, kc = (ch & 15) * 8;
        bf16x8 hv = *(const bf16x8*)(W2h + (size_t)n * 128 + kc);
        bf16x8 lv = *(const bf16x8*)(W2l + (size_t)n * 128 + kc);
        int byte = ((n * 128 + kc) * 2) ^ ((n & 7) << 4);
        *(bf16x8*)(WhC + byte) = hv;
        *(bf16x8*)(WlC + byte) = lv;
    }
    __syncthreads();

    // phase 2: logits = A2 @ w2 + b2
    f32x4 acc2[2][2];
#pragma unroll
    for (int mf = 0; mf < 2; ++mf)
#pragma unroll
        for (int nf = 0; nf < 2; ++nf) acc2[mf][nf] = (f32x4){0.f, 0.f, 0.f, 0.f};
#pragma unroll
    for (int ks = 0; ks < 4; ++ks) {
        bf16x8 a2[2], wh[2], wl[2];
#pragma unroll
        for (int mf = 0; mf < 2; ++mf) {
            int row = wrow * 32 + mf * 16 + l15;
            int byte = ((row * 128 + ks * 32 + l4 * 8) * 2) ^ ((row & 7) << 4);
            a2[mf] = *(const bf16x8*)(A2C + byte);
        }
#pragma unroll
        for (int nf = 0; nf < 2; ++nf) {
            int n = wcol * 32 + nf * 16 + l15;
            int byte = ((n * 128 + ks * 32 + l4 * 8) * 2) ^ ((n & 7) << 4);
            wh[nf] = *(const bf16x8*)(WhC + byte);
            wl[nf] = *(const bf16x8*)(WlC + byte);
        }
#pragma unroll
        for (int mf = 0; mf < 2; ++mf)
#pragma unroll
            for (int nf = 0; nf < 2; ++nf) {
                acc2[mf][nf] = __builtin_amdgcn_mfma_f32_16x16x32_bf16(a2[mf], wh[nf], acc2[mf][nf], 0, 0, 0);
                acc2[mf][nf] = __builtin_amdgcn_mfma_f32_16x16x32_bf16(a2[mf], wl[nf], acc2[mf][nf], 0, 0, 0);
            }
    }
#pragma unroll
    for (int mf = 0; mf < 2; ++mf) {
#pragma unroll
        for (int nf = 0; nf < 2; ++nf) {
            int col = wcol * 32 + nf * 16 + l15;
            float bv = b2[col];
#pragma unroll
            for (int r = 0; r < 4; ++r) {
                int grow = bm + wrow * 32 + mf * 16 + l4 * 4 + r;
                if (grow < M)
                    logits[(size_t)grow * D_OUT + col] = acc2[mf][nf][r] + bv;
            }
        }
    }
}

// ---------------- launch ----------------

extern "C" void kernel_launch(void* const* d_in, const int* in_sizes, int n_in,
                              void* d_out, int out_size, void* d_ws, size_t ws_size,
                              hipStream_t stream) {
    const float* x  = (const float*)d_in[0];
    const int*   ei = (const int*)d_in[1];
    const float* w1 = (const float*)d_in[2];
    const float* b1 = (const float*)d_in[3];
    const float* cw = (const float*)d_in[4];
    const float* w2 = (const float*)d_in[5];
    const float* b2 = (const float*)d_in[6];
    float* out = (float*)d_out;
    const int* rowp = ei;            // source nodes
    const int* colp = ei + N_EDGES;  // target nodes

    char* p = (char*)d_ws;
    auto alloc = [&](size_t bytes) -> void* {
        void* r = (void*)p;
        p += ((bytes + 255) / 256) * 256;
        return r;
    };
    int*   deg     = (int*)  alloc((size_t)N_NODES * 4);
    int*   cursor  = (int*)  alloc((size_t)N_NODES * 4);
    int*   offsets = (int*)  alloc((size_t)(N_NODES + 1) * 4);
    int*   partials= (int*)  alloc((size_t)SCAN_NB * 4);
    int2*  edges   = (int2*) alloc((size_t)N_EDGES * 8);
    float* dinv    = (float*)alloc((size_t)N_NODES * 4);
    unsigned short* zb  = (unsigned short*)alloc((size_t)N_NODES * H_DIM * 2);
    unsigned short* h0b = (unsigned short*)alloc((size_t)N_NODES * H_DIM * 2);
    unsigned short* h1b = (unsigned short*)alloc((size_t)N_NODES * H_DIM * 2);
    unsigned short* w1th = (unsigned short*)alloc((size_t)W1_E * 2);
    unsigned short* w1tl = (unsigned short*)alloc((size_t)W1_E * 2);
    unsigned short* cwth = (unsigned short*)alloc((size_t)CW_E * 2);
    unsigned short* cwtl = (unsigned short*)alloc((size_t)CW_E * 2);
    unsigned short* w2th = (unsigned short*)alloc((size_t)W2_E * 2);
    unsigned short* w2tl = (unsigned short*)alloc((size_t)W2_E * 2);

    float* h2     = out;                              // output 0: h [N,128]
    float* logits = out + (size_t)N_NODES * H_DIM;    // output 1: [N,64]

    // CSC build + weight prep
    hipLaunchKernelGGL(k_init, dim3((N_NODES + 255) / 256), dim3(256), 0, stream, deg, N_NODES);
    hipLaunchKernelGGL(k_mega_count_wprep, dim3(CNT_NB + WP_NB), dim3(256), 0, stream,
                       colp, deg, w1, cw, w2, w1th, w1tl, cwth, cwtl, w2th, w2tl);
    hipLaunchKernelGGL(k_scan_part,  dim3(SCAN_NB), dim3(SCAN_TPB), 0, stream, deg, partials, N_NODES);
    hipLaunchKernelGGL(k_scan_mid,   dim3(1), dim3(64), 0, stream, partials, offsets);
    hipLaunchKernelGGL(k_scan_write, dim3(SCAN_NB), dim3(SCAN_TPB), 0, stream,
                       deg, partials, offsets, cursor, dinv, N_NODES);

    // fill + lin1 co-scheduled
    hipLaunchKernelGGL(k_mega_fill_lin1, dim3(MEGA_B_NB), dim3(256), 0, stream,
                       rowp, colp, cursor, dinv, edges, x, w1th, w1tl, b1, h0b);

    int gemmGrid = (N_NODES + 63) / 64;
    int aggGrid = (int)(((size_t)N_NODES * 64 + 255) / 256);
    // layer 0
    hipLaunchKernelGGL(k_agg, dim3(aggGrid), dim3(256), 0, stream,
                       h0b, h0b, offsets, edges, dinv, zb, N_NODES);
    hipLaunchKernelGGL((k_mfma_gemm<128, false, false, false, false, true>), dim3(gemmGrid), dim3(256), 0, stream,
                       (const float*)nullptr, zb, cwth, cwtl, (const float*)nullptr,
                       (float*)nullptr, h1b, N_NODES, H_DIM);
    // layer 1
    hipLaunchKernelGGL(k_agg, dim3(aggGrid), dim3(256), 0, stream,
                       h1b, h0b, offsets, edges, dinv, zb, N_NODES);
    // conv1 + logits fused
    hipLaunchKernelGGL(k_conv1_logits, dim3(gemmGrid), dim3(256), 0, stream,
                       zb, cwth + H_DIM * H_DIM, cwtl + H_DIM * H_DIM,
                       w2th, w2tl, b2, h2, logits, N_NODES);
}